// Round 1
// baseline (144352.905 us; speedup 1.0000x reference)
//
#include <hip/hip_runtime.h>

#define NWG   256
#define NTHR  512
#define BB    32
#define SS    512
#define ID    512
#define HD    1024
#define OD    512
#define BH    (BB*HD)               // 32768 floats per hidden state
#define OUT_HID_OFF (BB*SS*OD)      // start of hidden_state in d_out

struct GruParams {
  const float *x;
  const float *Wxz0, *bxz0, *Whz0, *Wxr0, *bxr0, *Whr0, *Wxg0, *bxg0, *Whg0;
  const float *Wxz1, *bxz1, *Whz1, *Wxr1, *bxr1, *Whr1, *Wxg1, *bxg1, *Whg1;
  const float *Why, *bhy;
  float *out;
  float *h0buf, *h1buf;             // 2*BH each (double-buffered)
  float *z0, *r0, *z1, *r1;         // BH each
  unsigned *bar;                    // [0]=count, [1]=generation (memset to 0 per launch)
};

__device__ __forceinline__ float dot4(const float* __restrict__ w,
                                      const float* __restrict__ a,
                                      int k0, int k1) {
  float s0 = 0.f, s1 = 0.f, s2 = 0.f, s3 = 0.f;
  #pragma unroll 2
  for (int k = k0; k < k1; k += 4) {
    float4 wv = *(const float4*)(w + k);
    float4 av = *(const float4*)(a + k);
    s0 = fmaf(wv.x, av.x, s0);
    s1 = fmaf(wv.y, av.y, s1);
    s2 = fmaf(wv.z, av.z, s2);
    s3 = fmaf(wv.w, av.w, s3);
  }
  return (s0 + s1) + (s2 + s3);
}

__device__ __forceinline__ float dot4_rh(const float* __restrict__ w,
                                         const float* __restrict__ r,
                                         const float* __restrict__ h,
                                         int k0, int k1) {
  float s0 = 0.f, s1 = 0.f, s2 = 0.f, s3 = 0.f;
  #pragma unroll 2
  for (int k = k0; k < k1; k += 4) {
    float4 wv = *(const float4*)(w + k);
    float4 rv = *(const float4*)(r + k);
    float4 hv = *(const float4*)(h + k);
    s0 = fmaf(wv.x, rv.x * hv.x, s0);
    s1 = fmaf(wv.y, rv.y * hv.y, s1);
    s2 = fmaf(wv.z, rv.z * hv.z, s2);
    s3 = fmaf(wv.w, rv.w * hv.w, s3);
  }
  return (s0 + s1) + (s2 + s3);
}

// Device-scope sense(epoch) barrier. Spin uses RELAXED atomic loads (no
// per-poll cache invalidate); single acquire fence on exit.
__device__ __forceinline__ void gridbar(unsigned* bar, unsigned* gen_cnt) {
  __syncthreads();
  const unsigned g = ++(*gen_cnt);
  if (threadIdx.x == 0) {
    __threadfence();  // release: make this WG's writes device-visible
    unsigned arrived = __hip_atomic_fetch_add(&bar[0], 1u, __ATOMIC_ACQ_REL,
                                              __HIP_MEMORY_SCOPE_AGENT);
    if (arrived == NWG - 1u) {
      __hip_atomic_store(&bar[0], 0u, __ATOMIC_RELAXED, __HIP_MEMORY_SCOPE_AGENT);
      __hip_atomic_store(&bar[1], g, __ATOMIC_RELEASE, __HIP_MEMORY_SCOPE_AGENT);
    } else {
      while (__hip_atomic_load(&bar[1], __ATOMIC_RELAXED,
                               __HIP_MEMORY_SCOPE_AGENT) != g) {
        __builtin_amdgcn_s_sleep(1);
      }
    }
    __threadfence();  // acquire: invalidate stale cached lines
  }
  __syncthreads();
}

__global__ __launch_bounds__(NTHR) void gru_persistent(GruParams p) {
  __shared__ float lds[NTHR];
  const int tid  = threadIdx.x;
  const int blk  = blockIdx.x;
  const int gtid = blk * NTHR + tid;
  unsigned gen = 0;

  // zero initial hidden state (parity-0 buffers)
  if (gtid < BH)           p.h0buf[gtid] = 0.f;
  else if (gtid < 2 * BH)  p.h1buf[gtid - BH] = 0.f;
  gridbar(p.bar, &gen);

  for (int t = 0; t < SS; ++t) {
    const int par = t & 1;
    const float* __restrict__ h0_old = p.h0buf + par * BH;
    float* __restrict__       h0_new = p.h0buf + (par ^ 1) * BH;
    const float* __restrict__ h1_old = p.h1buf + par * BH;
    float* __restrict__       h1_new = p.h1buf + (par ^ 1) * BH;

    // ---------- P1: layer-0 z, r (x-side inline). 65536 outputs, K-split 2.
    {
      const int o = tid & 255, q = tid >> 8;
      const int idx = blk * 256 + o;                 // gate|b|j — gate,b uniform per WG
      const int gate = idx >> 15;
      const int b = (idx >> 10) & 31;
      const int j = idx & 1023;
      const float* Wx = gate ? p.Wxr0 : p.Wxz0;
      const float* Wh = gate ? p.Whr0 : p.Whz0;
      const float* xrow = p.x + (size_t)b * (SS * ID) + (size_t)t * ID;
      const float* hrow = h0_old + b * HD;
      const int k0 = q * 768, k1 = k0 + 768;         // unified K = 512(x)+1024(h)
      float acc = 0.f;
      const int xe = k1 < ID ? k1 : ID;
      if (k0 < xe) acc += dot4(Wx + (size_t)j * ID, xrow, k0, xe);
      const int ha = (k0 > ID ? k0 : ID) - ID;
      const int hb = k1 - ID;
      if (ha < hb) acc += dot4(Wh + (size_t)j * HD, hrow, ha, hb);
      lds[tid] = acc;
    }
    __syncthreads();
    if (tid < 256) {
      const int idx = blk * 256 + tid;
      const int gate = idx >> 15;
      const int b = (idx >> 10) & 31;
      const int j = idx & 1023;
      const float bias = gate ? p.bxr0[j] : p.bxz0[j];
      const float v = lds[tid] + lds[tid + 256] + bias;
      (gate ? p.r0 : p.z0)[b * HD + j] = 1.f / (1.f + expf(-v));
    }
    gridbar(p.bar, &gen);

    // ---------- P2: layer-0 g + h0 update. 32768 outputs, K-split 4.
    {
      const int o = tid & 127, q = tid >> 7;
      const int idx = blk * 128 + o;
      const int b = idx >> 10;
      const int j = idx & 1023;
      const float* xrow = p.x + (size_t)b * (SS * ID) + (size_t)t * ID;
      const float* hrow = h0_old + b * HD;
      const float* rrow = p.r0 + b * HD;
      const int k0 = q * 384, k1 = k0 + 384;
      float acc = 0.f;
      const int xe = k1 < ID ? k1 : ID;
      if (k0 < xe) acc += dot4(p.Wxg0 + (size_t)j * ID, xrow, k0, xe);
      const int ha = (k0 > ID ? k0 : ID) - ID;
      const int hb = k1 - ID;
      if (ha < hb) acc += dot4_rh(p.Whg0 + (size_t)j * HD, rrow, hrow, ha, hb);
      lds[tid] = acc;
    }
    __syncthreads();
    if (tid < 128) {
      const int idx = blk * 128 + tid;
      const int b = idx >> 10;
      const int j = idx & 1023;
      const float v = lds[tid] + lds[tid + 128] + lds[tid + 256] + lds[tid + 384]
                      + p.bxg0[j];
      const float g0 = tanhf(v);
      const float z  = p.z0[b * HD + j];
      const float ho = h0_old[b * HD + j];
      h0_new[b * HD + j] = z * ho + (1.f - z) * g0;
    }
    gridbar(p.bar, &gen);

    // ---------- P3: layer-1 z, r (x-side = h0_new, h-side = h1_old). K-split 2.
    {
      const int o = tid & 255, q = tid >> 8;
      const int idx = blk * 256 + o;
      const int gate = idx >> 15;
      const int b = (idx >> 10) & 31;
      const int j = idx & 1023;
      const float* W;
      const float* arow;
      if (q == 0) { W = gate ? p.Wxr1 : p.Wxz1; arow = h0_new + b * HD; }
      else        { W = gate ? p.Whr1 : p.Whz1; arow = h1_old + b * HD; }
      lds[tid] = dot4(W + (size_t)j * HD, arow, 0, HD);
    }
    __syncthreads();
    if (tid < 256) {
      const int idx = blk * 256 + tid;
      const int gate = idx >> 15;
      const int b = (idx >> 10) & 31;
      const int j = idx & 1023;
      const float bias = gate ? p.bxr1[j] : p.bxz1[j];
      const float v = lds[tid] + lds[tid + 256] + bias;
      (gate ? p.r1 : p.z1)[b * HD + j] = 1.f / (1.f + expf(-v));
    }
    gridbar(p.bar, &gen);

    // ---------- P4: layer-1 g + h1 update, plus y_{t-1} from h1_old.
    // No grid barrier after this phase: it overlaps next step's P1.
    if (tid < 256) {
      const int o = tid & 127, q = tid >> 7;
      const int idx = blk * 128 + o;
      const int b = idx >> 10;
      const int j = idx & 1023;
      float acc;
      if (q == 0) acc = dot4(p.Wxg1 + (size_t)j * HD, h0_new + b * HD, 0, HD);
      else        acc = dot4_rh(p.Whg1 + (size_t)j * HD, p.r1 + b * HD,
                                h1_old + b * HD, 0, HD);
      lds[tid] = acc;
    } else if (tid < 384) {
      const int l = tid - 256;
      const int o = l & 63, q = l >> 6;
      const int idx = blk * 64 + o;
      const int b = idx >> 9;
      const int col = idx & 511;
      lds[tid] = dot4(p.Why + (size_t)col * HD, h1_old + b * HD,
                      q * 512, q * 512 + 512);
    }
    __syncthreads();
    if (tid < 128) {
      const int idx = blk * 128 + tid;
      const int b = idx >> 10;
      const int j = idx & 1023;
      const float v = lds[tid] + lds[tid + 128] + p.bxg1[j];
      const float g1 = tanhf(v);
      const float z  = p.z1[b * HD + j];
      const float ho = h1_old[b * HD + j];
      h1_new[b * HD + j] = z * ho + (1.f - z) * g1;
    } else if (tid < 192) {
      if (t > 0) {
        const int o = tid - 128;
        const int idx = blk * 64 + o;
        const int b = idx >> 9;
        const int col = idx & 511;
        const float y = lds[256 + o] + lds[320 + o] + p.bhy[col];
        p.out[(size_t)b * (SS * OD) + (size_t)(t - 1) * OD + col] = y;
      }
    }
    __syncthreads();   // LDS reuse guard before next step's P1
  }

  gridbar(p.bar, &gen);

  // Finalize: y at t = SS-1, then hidden_state (B, 2, H).
  const float* h0f = p.h0buf;   // SS even -> final state in parity-0 buffers
  const float* h1f = p.h1buf;
  if (gtid < BB * OD) {
    const int b = gtid >> 9;
    const int col = gtid & 511;
    const float y = p.bhy[col] + dot4(p.Why + (size_t)col * HD, h1f + b * HD, 0, HD);
    p.out[(size_t)b * (SS * OD) + (size_t)(SS - 1) * OD + col] = y;
  } else if (gtid < BB * OD + BH) {
    const int e = gtid - BB * OD;
    const int b = e >> 10, j = e & 1023;
    p.out[OUT_HID_OFF + (size_t)b * (2 * HD) + j] = h0f[b * HD + j];
  } else if (gtid < BB * OD + 2 * BH) {
    const int e = gtid - BB * OD - BH;
    const int b = e >> 10, j = e & 1023;
    p.out[OUT_HID_OFF + (size_t)b * (2 * HD) + HD + j] = h1f[b * HD + j];
  }
}

extern "C" void kernel_launch(void* const* d_in, const int* in_sizes, int n_in,
                              void* d_out, int out_size, void* d_ws, size_t ws_size,
                              hipStream_t stream) {
  GruParams P;
  P.x    = (const float*)d_in[0];
  P.Wxz0 = (const float*)d_in[1];  P.bxz0 = (const float*)d_in[2];  P.Whz0 = (const float*)d_in[3];
  P.Wxr0 = (const float*)d_in[4];  P.bxr0 = (const float*)d_in[5];  P.Whr0 = (const float*)d_in[6];
  P.Wxg0 = (const float*)d_in[7];  P.bxg0 = (const float*)d_in[8];  P.Whg0 = (const float*)d_in[9];
  P.Wxz1 = (const float*)d_in[10]; P.bxz1 = (const float*)d_in[11]; P.Whz1 = (const float*)d_in[12];
  P.Wxr1 = (const float*)d_in[13]; P.bxr1 = (const float*)d_in[14]; P.Whr1 = (const float*)d_in[15];
  P.Wxg1 = (const float*)d_in[16]; P.bxg1 = (const float*)d_in[17]; P.Whg1 = (const float*)d_in[18];
  P.Why  = (const float*)d_in[19]; P.bhy  = (const float*)d_in[20];
  P.out  = (float*)d_out;

  float* ws = (float*)d_ws;
  P.h0buf = ws;                 // 2*BH
  P.h1buf = ws + 2 * BH;        // 2*BH
  P.z0    = ws + 4 * BH;
  P.r0    = ws + 5 * BH;
  P.z1    = ws + 6 * BH;
  P.r1    = ws + 7 * BH;
  P.bar   = (unsigned*)(ws + 8 * BH);

  hipMemsetAsync(P.bar, 0, 2 * sizeof(unsigned), stream);

  void* args[] = { &P };
  hipLaunchCooperativeKernel((const void*)gru_persistent,
                             dim3(NWG), dim3(NTHR), args, 0, stream);
}

// Round 2
// 80600.049 us; speedup vs baseline: 1.7910x; 1.7910x over previous
//
#include <hip/hip_runtime.h>

#define NWG   256
#define NTHR  512
#define BB    32
#define SS    512
#define ID    512
#define HD    1024
#define OD    512
#define OUT_HID_OFF (BB*SS*OD)   // 8388608

// packed transposed-weight buffer sizes (floats)
#define WT_ZR0_SZ (1536*2048)
#define WT_G0_SZ  (1536*1024)
#define WT_ZR1_SZ (2048*2048)
#define WT_G1_SZ  (2048*1024)
#define WT_Y_SZ   (1024*512)
// partial buffers (floats): [kt][32 b][N]
#define P_ZR0_SZ (12*32*2048)
#define P_G0_SZ  (12*32*1024)
#define P_ZR1_SZ (16*32*2048)
#define P_G1_SZ  (16*32*1024)
#define P_Y_SZ   (8*32*512)

struct GP {
  const float *x;
  const float *Wxz0, *bxz0, *Whz0, *Wxr0, *bxr0, *Whr0, *Wxg0, *bxg0, *Whg0;
  const float *Wxz1, *bxz1, *Whz1, *Wxr1, *bxr1, *Whr1, *Wxg1, *bxg1, *Whg1;
  const float *Why, *bhy;
  float *out;
  float *wt_zr0, *wt_g0, *wt_zr1, *wt_g1, *wt_y;
  float *p_zr0, *p_g0, *p_zr1, *p_g1, *p_y;
  float *h0buf, *h1buf;             // 2 parities * 32768 each
  float *z0, *r0, *z1, *r1;         // 32768 each
  unsigned *bar;
};

// ---------------- one-time packed weight transpose (64x64 LDS tiles) --------
__global__ __launch_bounds__(256) void transp(GP p) {
  __shared__ float t[64*65];
  const int v = blockIdx.x;
  const int tx = threadIdx.x & 63, ty = threadIdx.x >> 6;
  const float* src; float* dst;
  int srcK, srow, scol, N, k0, n0;
  if (v < 768) {                      // wt_zr0: K=1536 (24 kt) x N=2048 (32 nt)
    int kt = v >> 5, nt = v & 31; k0 = kt*64; n0 = nt*64; N = 2048; dst = p.wt_zr0;
    if (k0 < 512) { srcK = 512;  scol = k0;       src = (n0 < 1024) ? p.Wxz0 : p.Wxr0; }
    else          { srcK = 1024; scol = k0 - 512; src = (n0 < 1024) ? p.Whz0 : p.Whr0; }
    srow = n0 & 1023;
  } else if (v < 1152) {              // wt_g0: 24 x 16
    int u = v - 768; int kt = u >> 4, nt = u & 15; k0 = kt*64; n0 = nt*64; N = 1024; dst = p.wt_g0;
    if (k0 < 512) { srcK = 512;  scol = k0;       src = p.Wxg0; }
    else          { srcK = 1024; scol = k0 - 512; src = p.Whg0; }
    srow = n0;
  } else if (v < 2176) {              // wt_zr1: 32 x 32
    int u = v - 1152; int kt = u >> 5, nt = u & 31; k0 = kt*64; n0 = nt*64; N = 2048; dst = p.wt_zr1;
    srcK = 1024;
    if (k0 < 1024) { scol = k0;        src = (n0 < 1024) ? p.Wxz1 : p.Wxr1; }
    else           { scol = k0 - 1024; src = (n0 < 1024) ? p.Whz1 : p.Whr1; }
    srow = n0 & 1023;
  } else if (v < 2688) {              // wt_g1: 32 x 16
    int u = v - 2176; int kt = u >> 4, nt = u & 15; k0 = kt*64; n0 = nt*64; N = 1024; dst = p.wt_g1;
    srcK = 1024;
    if (k0 < 1024) { scol = k0;        src = p.Wxg1; }
    else           { scol = k0 - 1024; src = p.Whg1; }
    srow = n0;
  } else {                            // wt_y: 16 x 8
    int u = v - 2688; int kt = u >> 3, nt = u & 7; k0 = kt*64; n0 = nt*64; N = 512; dst = p.wt_y;
    srcK = 1024; scol = k0; src = p.Why; srow = n0;
  }
  #pragma unroll
  for (int q = 0; q < 16; ++q) {
    int r = (q << 2) + ty;            // 0..63 (n within tile)
    t[tx*65 + r] = src[(size_t)(srow + r)*srcK + scol + tx];
  }
  __syncthreads();
  #pragma unroll
  for (int q = 0; q < 16; ++q) {
    int kk = (q << 2) + ty;           // 0..63 (k within tile)
    dst[(size_t)(k0 + kk)*N + n0 + tx] = t[kk*65 + tx];
  }
}

// ---------------- grid barrier ----------------------------------------------
__device__ __forceinline__ void gridbar(unsigned* bar, unsigned* gen_cnt) {
  __syncthreads();
  const unsigned g = ++(*gen_cnt);
  if (threadIdx.x == 0) {
    __threadfence();
    unsigned arrived = __hip_atomic_fetch_add(&bar[0], 1u, __ATOMIC_ACQ_REL,
                                              __HIP_MEMORY_SCOPE_AGENT);
    if (arrived == NWG - 1u) {
      __hip_atomic_store(&bar[0], 0u, __ATOMIC_RELAXED, __HIP_MEMORY_SCOPE_AGENT);
      __hip_atomic_store(&bar[1], g, __ATOMIC_RELEASE, __HIP_MEMORY_SCOPE_AGENT);
    } else {
      while (__hip_atomic_load(&bar[1], __ATOMIC_RELAXED,
                               __HIP_MEMORY_SCOPE_AGENT) != g) {
        __builtin_amdgcn_s_sleep(1);
      }
    }
    __threadfence();
  }
  __syncthreads();
}

// ---------------- GEMM unit: 32b x 256j x 128k, thread tile 4b x 4j ---------
__device__ __forceinline__ float4 f4fma(float s, float4 v, float4 c) {
  c.x = fmaf(s, v.x, c.x); c.y = fmaf(s, v.y, c.y);
  c.z = fmaf(s, v.z, c.z); c.w = fmaf(s, v.w, c.w);
  return c;
}

__device__ __forceinline__ void gemm_unit(const float* __restrict__ WT, int N,
                                          int kt, int jt,
                                          const float* __restrict__ A,
                                          float* __restrict__ part) {
  const int tb = threadIdx.x >> 6;        // wave id 0..7 -> b-group
  const int tj = threadIdx.x & 63;        // 64 j-groups
  const int col0 = jt*256 + tj*4;
  const float* w0 = WT + (size_t)(kt*128)*N + col0;
  const float* arow = A + (tb*4)*132;
  float4 acc[4];
  #pragma unroll
  for (int m = 0; m < 4; ++m) acc[m] = make_float4(0.f, 0.f, 0.f, 0.f);
  for (int kk = 0; kk < 32; ++kk) {
    float4 w[4];
    #pragma unroll
    for (int r = 0; r < 4; ++r)
      w[r] = *(const float4*)(w0 + (size_t)(4*kk + r)*N);
    #pragma unroll
    for (int m = 0; m < 4; ++m) {
      float4 a = *(const float4*)(arow + m*132 + 4*kk);   // wave-uniform broadcast
      acc[m] = f4fma(a.x, w[0], acc[m]);
      acc[m] = f4fma(a.y, w[1], acc[m]);
      acc[m] = f4fma(a.z, w[2], acc[m]);
      acc[m] = f4fma(a.w, w[3], acc[m]);
    }
  }
  #pragma unroll
  for (int m = 0; m < 4; ++m)
    *(float4*)(part + (size_t)(kt*32 + tb*4 + m)*N + col0) = acc[m];
}

// ---------------- A-tile staging: 32 rows x 128 cols into LDS (pad 132) -----
__device__ __forceinline__ void stage_plain(float* A, const float* __restrict__ src,
                                            size_t stride) {
  const int r = threadIdx.x >> 4, c0 = (threadIdx.x & 15) * 8;
  const float* s = src + (size_t)r*stride + c0;
  float4 v0 = *(const float4*)s, v1 = *(const float4*)(s + 4);
  *(float4*)(A + r*132 + c0)     = v0;
  *(float4*)(A + r*132 + c0 + 4) = v1;
}

__device__ __forceinline__ void stage_rh(float* A, const float* __restrict__ rr,
                                         const float* __restrict__ hh) {
  const int r = threadIdx.x >> 4, c0 = (threadIdx.x & 15) * 8;
  const float* pr = rr + (size_t)r*HD + c0;
  const float* ph = hh + (size_t)r*HD + c0;
  float4 a0 = *(const float4*)pr, a1 = *(const float4*)(pr + 4);
  float4 b0 = *(const float4*)ph, b1 = *(const float4*)(ph + 4);
  a0.x *= b0.x; a0.y *= b0.y; a0.z *= b0.z; a0.w *= b0.w;
  a1.x *= b1.x; a1.y *= b1.y; a1.z *= b1.z; a1.w *= b1.w;
  *(float4*)(A + r*132 + c0)     = a0;
  *(float4*)(A + r*132 + c0 + 4) = a1;
}

__device__ __forceinline__ float sigmf(float v) { return 1.f / (1.f + expf(-v)); }

// ---------------- main persistent kernel ------------------------------------
__global__ __launch_bounds__(NTHR) void gru_main(GP p) {
  __shared__ float A[32*132];
  const int tid = threadIdx.x, wg = blockIdx.x;
  unsigned gen = 0;

  { int gt = wg*NTHR + tid;              // zero both parities of h0,h1 (131072)
    if (gt < 65536) p.h0buf[gt] = 0.f; else p.h1buf[gt - 65536] = 0.f; }
  gridbar(p.bar, &gen);

  for (int i = 0; i < SS + 2; ++i) {
    const int a = i, s = i - 1, c = i - 2;
    const bool va = (a < SS), vs = (s >= 0 && s < SS), vc = (c >= 0 && c < SS);
    const float* h0_prev  = p.h0buf + (size_t)((i - 1) & 1) * 32768;  // h0(i-1)
    float*       h0_cur   = p.h0buf + (size_t)(i & 1) * 32768;        // h0(i) dest
    const float* h1_prev2 = p.h1buf + (size_t)(i & 1) * 32768;        // h1(i-2)
    float*       h1_w     = p.h1buf + (size_t)((i - 1) & 1) * 32768;  // h1(i-1) dest

    // ===== S1: G_zr0(a) [96 units] | G_zr1(s) [128 units] ====================
    if (wg < 96) { if (va) {
        const int kt = wg >> 3, jt = wg & 7;
        if (kt < 4) stage_plain(A, p.x + (size_t)a*ID + kt*128, (size_t)SS*ID);
        else        stage_plain(A, h0_prev + (kt*128 - 512), HD);
        __syncthreads();
        gemm_unit(p.wt_zr0, 2048, kt, jt, A, p.p_zr0);
    }} else if (wg < 224) { if (vs) {
        const int u = wg - 96, kt = u >> 3, jt = u & 7;
        if (kt < 8) stage_plain(A, h0_prev + kt*128, HD);
        else        stage_plain(A, h1_prev2 + (kt*128 - 1024), HD);
        __syncthreads();
        gemm_unit(p.wt_zr1, 2048, kt, jt, A, p.p_zr1);
    }}
    gridbar(p.bar, &gen);

    // ===== S2: R_zr0(a) | R_zr1(s) ==========================================
    { const int o = wg*NTHR + tid;
      if (o < 65536) { if (va) {
          const int b = o >> 11, col = o & 2047;
          float v = (col < 1024) ? p.bxz0[col] : p.bxr0[col - 1024];
          #pragma unroll
          for (int kt = 0; kt < 12; ++kt) v += p.p_zr0[(size_t)(kt*32 + b)*2048 + col];
          const float sg = sigmf(v);
          if (col < 1024) p.z0[b*HD + col] = sg; else p.r0[b*HD + col - 1024] = sg;
      }} else { if (vs) {
          const int o2 = o - 65536, b = o2 >> 11, col = o2 & 2047;
          float v = (col < 1024) ? p.bxz1[col] : p.bxr1[col - 1024];
          #pragma unroll
          for (int kt = 0; kt < 16; ++kt) v += p.p_zr1[(size_t)(kt*32 + b)*2048 + col];
          const float sg = sigmf(v);
          if (col < 1024) p.z1[b*HD + col] = sg; else p.r1[b*HD + col - 1024] = sg;
      }}}
    gridbar(p.bar, &gen);

    // ===== S3: G_g0(a) [48] | G_g1(s) [64] | G_y(c) [16] =====================
    if (wg < 48) { if (va) {
        const int kt = wg >> 2, jt = wg & 3;
        if (kt < 4) stage_plain(A, p.x + (size_t)a*ID + kt*128, (size_t)SS*ID);
        else        stage_rh(A, p.r0 + (kt*128 - 512), h0_prev + (kt*128 - 512));
        __syncthreads();
        gemm_unit(p.wt_g0, 1024, kt, jt, A, p.p_g0);
    }} else if (wg < 112) { if (vs) {
        const int u = wg - 48, kt = u >> 2, jt = u & 3;
        if (kt < 8) stage_plain(A, h0_prev + kt*128, HD);
        else        stage_rh(A, p.r1 + (kt*128 - 1024), h1_prev2 + (kt*128 - 1024));
        __syncthreads();
        gemm_unit(p.wt_g1, 1024, kt, jt, A, p.p_g1);
    }} else if (wg < 128) { if (vc) {
        const int u = wg - 112, kt = u >> 1, jt = u & 1;
        stage_plain(A, h1_prev2 + kt*128, HD);
        __syncthreads();
        gemm_unit(p.wt_y, 512, kt, jt, A, p.p_y);
    }}
    gridbar(p.bar, &gen);

    // ===== S4: R_g0(a)->h0 | R_g1(s)->h1 | R_y(c)->out ======================
    { const int o = wg*NTHR + tid;
      if (o < 32768) { if (va) {
          const int b = o >> 10, j = o & 1023;
          float v = p.bxg0[j];
          #pragma unroll
          for (int kt = 0; kt < 12; ++kt) v += p.p_g0[(size_t)(kt*32 + b)*1024 + j];
          const float g = tanhf(v);
          const float z = p.z0[o];
          const float ho = h0_prev[o];
          h0_cur[o] = z*ho + (1.f - z)*g;
      }} else if (o < 65536) { if (vs) {
          const int o2 = o - 32768, b = o2 >> 10, j = o2 & 1023;
          float v = p.bxg1[j];
          #pragma unroll
          for (int kt = 0; kt < 16; ++kt) v += p.p_g1[(size_t)(kt*32 + b)*1024 + j];
          const float g = tanhf(v);
          const float z = p.z1[o2];
          const float ho = h1_prev2[o2];
          h1_w[o2] = z*ho + (1.f - z)*g;
      }} else if (o < 81920) { if (vc) {
          const int o2 = o - 65536, b = o2 >> 9, col = o2 & 511;
          float v = p.bhy[col];
          #pragma unroll
          for (int kt = 0; kt < 8; ++kt) v += p.p_y[(size_t)(kt*32 + b)*512 + col];
          p.out[(size_t)b*(SS*OD) + (size_t)c*OD + col] = v;
      }}}
    gridbar(p.bar, &gen);
  }

  // final hidden state: h0(511), h1(511) both live in parity-1 buffers
  { const int o = wg*NTHR + tid;
    if (o < 65536) {
      const int b = o >> 11, r2 = o & 2047, l = r2 >> 10, h = r2 & 1023;
      const float* hb = (l ? p.h1buf : p.h0buf) + 32768;
      p.out[OUT_HID_OFF + (size_t)b*2048 + l*1024 + h] = hb[b*HD + h];
    } }
}

// ---------------- host launch ------------------------------------------------
extern "C" void kernel_launch(void* const* d_in, const int* in_sizes, int n_in,
                              void* d_out, int out_size, void* d_ws, size_t ws_size,
                              hipStream_t stream) {
  GP P;
  P.x    = (const float*)d_in[0];
  P.Wxz0 = (const float*)d_in[1];  P.bxz0 = (const float*)d_in[2];  P.Whz0 = (const float*)d_in[3];
  P.Wxr0 = (const float*)d_in[4];  P.bxr0 = (const float*)d_in[5];  P.Whr0 = (const float*)d_in[6];
  P.Wxg0 = (const float*)d_in[7];  P.bxg0 = (const float*)d_in[8];  P.Whg0 = (const float*)d_in[9];
  P.Wxz1 = (const float*)d_in[10]; P.bxz1 = (const float*)d_in[11]; P.Whz1 = (const float*)d_in[12];
  P.Wxr1 = (const float*)d_in[13]; P.bxr1 = (const float*)d_in[14]; P.Whr1 = (const float*)d_in[15];
  P.Wxg1 = (const float*)d_in[16]; P.bxg1 = (const float*)d_in[17]; P.Whg1 = (const float*)d_in[18];
  P.Why  = (const float*)d_in[19]; P.bhy  = (const float*)d_in[20];
  P.out  = (float*)d_out;

  float* ws = (float*)d_ws;
  size_t off = 0;
  P.wt_zr0 = ws + off; off += WT_ZR0_SZ;
  P.wt_g0  = ws + off; off += WT_G0_SZ;
  P.wt_zr1 = ws + off; off += WT_ZR1_SZ;
  P.wt_g1  = ws + off; off += WT_G1_SZ;
  P.wt_y   = ws + off; off += WT_Y_SZ;
  P.p_zr0  = ws + off; off += P_ZR0_SZ;
  P.p_g0   = ws + off; off += P_G0_SZ;
  P.p_zr1  = ws + off; off += P_ZR1_SZ;
  P.p_g1   = ws + off; off += P_G1_SZ;
  P.p_y    = ws + off; off += P_Y_SZ;
  P.h0buf  = ws + off; off += 2*32768;
  P.h1buf  = ws + off; off += 2*32768;
  P.z0     = ws + off; off += 32768;
  P.r0     = ws + off; off += 32768;
  P.z1     = ws + off; off += 32768;
  P.r1     = ws + off; off += 32768;
  P.bar    = (unsigned*)(ws + off);

  hipMemsetAsync(P.bar, 0, 2*sizeof(unsigned), stream);

  transp<<<dim3(2816), dim3(256), 0, stream>>>(P);

  void* args[] = { &P };
  hipLaunchCooperativeKernel((const void*)gru_main,
                             dim3(NWG), dim3(NTHR), args, 0, stream);
}

// Round 3
// 33914.639 us; speedup vs baseline: 4.2564x; 2.3766x over previous
//
#include <hip/hip_runtime.h>

#define NWG   256
#define NTHR  512
#define BB    32
#define SS    512
#define ID    512
#define HD    1024
#define OD    512
#define OUT_HID_OFF (BB*SS*OD)   // 8388608

// packed transposed-weight buffer sizes (floats)
#define WT_ZR0_SZ (1536*2048)
#define WT_G0_SZ  (1536*1024)
#define WT_ZR1_SZ (2048*2048)
#define WT_G1_SZ  (2048*1024)
#define WT_Y_SZ   (1024*512)
// partial buffers (floats): [kt][32 b][N]
#define P_ZR0_SZ (12*32*2048)
#define P_G0_SZ  (12*32*1024)
#define P_ZR1_SZ (16*32*2048)
#define P_G1_SZ  (16*32*1024)
#define P_Y_SZ   (8*32*512)

#define FLAG_STRIDE 32   // 128 B per flag line

struct GP {
  const float *x;
  const float *Wxz0, *bxz0, *Whz0, *Wxr0, *bxr0, *Whr0, *Wxg0, *bxg0, *Whg0;
  const float *Wxz1, *bxz1, *Whz1, *Wxr1, *bxr1, *Whr1, *Wxg1, *bxg1, *Whg1;
  const float *Why, *bhy;
  float *out;
  float *wt_zr0, *wt_g0, *wt_zr1, *wt_g1, *wt_y;
  float *p_zr0, *p_g0, *p_zr1, *p_g1, *p_y;
  float *h0buf, *h1buf;             // 2 parities * 32768 each
  float *z0, *r0, *z1, *r1;         // 32768 each
  unsigned *flags;                  // NWG * FLAG_STRIDE
  unsigned *bar_gen;                // 1
};

// ---- agent-scope (LLC-coherent, L2-write-through) accessors for MUTABLE data
__device__ __forceinline__ float aload(const float* p) {
  return __hip_atomic_load(p, __ATOMIC_RELAXED, __HIP_MEMORY_SCOPE_AGENT);
}
__device__ __forceinline__ void astore(float* p, float v) {
  __hip_atomic_store(p, v, __ATOMIC_RELAXED, __HIP_MEMORY_SCOPE_AGENT);
}

// ---------------- one-time packed weight transpose (64x64 LDS tiles) --------
__global__ __launch_bounds__(256) void transp(GP p) {
  __shared__ float t[64*65];
  const int v = blockIdx.x;
  const int tx = threadIdx.x & 63, ty = threadIdx.x >> 6;
  const float* src; float* dst;
  int srcK, srow, scol, N, k0, n0;
  if (v < 768) {                      // wt_zr0: K=1536 (24 kt) x N=2048 (32 nt)
    int kt = v >> 5, nt = v & 31; k0 = kt*64; n0 = nt*64; N = 2048; dst = p.wt_zr0;
    if (k0 < 512) { srcK = 512;  scol = k0;       src = (n0 < 1024) ? p.Wxz0 : p.Wxr0; }
    else          { srcK = 1024; scol = k0 - 512; src = (n0 < 1024) ? p.Whz0 : p.Whr0; }
    srow = n0 & 1023;
  } else if (v < 1152) {              // wt_g0: 24 x 16
    int u = v - 768; int kt = u >> 4, nt = u & 15; k0 = kt*64; n0 = nt*64; N = 1024; dst = p.wt_g0;
    if (k0 < 512) { srcK = 512;  scol = k0;       src = p.Wxg0; }
    else          { srcK = 1024; scol = k0 - 512; src = p.Whg0; }
    srow = n0;
  } else if (v < 2176) {              // wt_zr1: 32 x 32
    int u = v - 1152; int kt = u >> 5, nt = u & 31; k0 = kt*64; n0 = nt*64; N = 2048; dst = p.wt_zr1;
    srcK = 1024;
    if (k0 < 1024) { scol = k0;        src = (n0 < 1024) ? p.Wxz1 : p.Wxr1; }
    else           { scol = k0 - 1024; src = (n0 < 1024) ? p.Whz1 : p.Whr1; }
    srow = n0 & 1023;
  } else if (v < 2688) {              // wt_g1: 32 x 16
    int u = v - 2176; int kt = u >> 4, nt = u & 15; k0 = kt*64; n0 = nt*64; N = 1024; dst = p.wt_g1;
    srcK = 1024;
    if (k0 < 1024) { scol = k0;        src = p.Wxg1; }
    else           { scol = k0 - 1024; src = p.Whg1; }
    srow = n0;
  } else {                            // wt_y: 16 x 8
    int u = v - 2688; int kt = u >> 3, nt = u & 7; k0 = kt*64; n0 = nt*64; N = 512; dst = p.wt_y;
    srcK = 1024; scol = k0; src = p.Why; srow = n0;
  }
  #pragma unroll
  for (int q = 0; q < 16; ++q) {
    int r = (q << 2) + ty;            // 0..63 (n within tile)
    t[tx*65 + r] = src[(size_t)(srow + r)*srcK + scol + tx];
  }
  __syncthreads();
  #pragma unroll
  for (int q = 0; q < 16; ++q) {
    int kk = (q << 2) + ty;           // 0..63 (k within tile)
    dst[(size_t)(k0 + kk)*N + n0 + tx] = t[kk*65 + tx];
  }
}

// ---------------- contention-free grid barrier ------------------------------
// Per-WG flag line (no RMW, no cacheline bouncing) + master gather + one
// read-shared release word. NO __threadfence: all cross-WG mutable data goes
// through agent-scope atomics (write-through LLC), and __syncthreads drains
// each wave's vmcnt before lane 0 signals. Plain cached weight loads stay
// resident in per-XCD L2 across steps (no fence-induced eviction).
__device__ __forceinline__ void gridbar(const GP& p, unsigned* gen_cnt) {
  __syncthreads();                    // all waves drained (vmcnt 0 each)
  const unsigned g = ++(*gen_cnt);
  if (blockIdx.x == 0) {
    if (threadIdx.x > 0 && threadIdx.x < NWG) {
      const unsigned* f = p.flags + (size_t)threadIdx.x * FLAG_STRIDE;
      while (__hip_atomic_load(f, __ATOMIC_RELAXED, __HIP_MEMORY_SCOPE_AGENT) < g)
        __builtin_amdgcn_s_sleep(2);
    }
    __syncthreads();                  // all 255 remote flags observed
    if (threadIdx.x == 0)
      __hip_atomic_store(p.bar_gen, g, __ATOMIC_RELAXED, __HIP_MEMORY_SCOPE_AGENT);
  } else {
    if (threadIdx.x == 0) {
      __hip_atomic_store(p.flags + (size_t)blockIdx.x * FLAG_STRIDE, g,
                         __ATOMIC_RELEASE, __HIP_MEMORY_SCOPE_AGENT);
      while (__hip_atomic_load(p.bar_gen, __ATOMIC_RELAXED,
                               __HIP_MEMORY_SCOPE_AGENT) < g)
        __builtin_amdgcn_s_sleep(2);
    }
  }
  asm volatile("" ::: "memory");      // compiler barrier: no hoisting past spin
  __syncthreads();
}

// ---------------- GEMM unit: 32b x 256j x 128k, thread tile 4b x 4j ---------
__device__ __forceinline__ float4 f4fma(float s, float4 v, float4 c) {
  c.x = fmaf(s, v.x, c.x); c.y = fmaf(s, v.y, c.y);
  c.z = fmaf(s, v.z, c.z); c.w = fmaf(s, v.w, c.w);
  return c;
}

__device__ __forceinline__ void gemm_unit(const float* __restrict__ WT, int N,
                                          int kt, int jt,
                                          const float* __restrict__ A,
                                          float* __restrict__ part) {
  const int tb = threadIdx.x >> 6;        // wave id 0..7 -> b-group
  const int tj = threadIdx.x & 63;        // 64 j-groups
  const int col0 = jt*256 + tj*4;
  const float* w0 = WT + (size_t)(kt*128)*N + col0;
  const float* arow = A + (tb*4)*132;
  float4 acc[4];
  #pragma unroll
  for (int m = 0; m < 4; ++m) acc[m] = make_float4(0.f, 0.f, 0.f, 0.f);
  #pragma unroll 2
  for (int kk = 0; kk < 32; ++kk) {
    float4 w[4];
    #pragma unroll
    for (int r = 0; r < 4; ++r)
      w[r] = *(const float4*)(w0 + (size_t)(4*kk + r)*N);   // plain: L2-cached
    #pragma unroll
    for (int m = 0; m < 4; ++m) {
      float4 a = *(const float4*)(arow + m*132 + 4*kk);     // LDS broadcast
      acc[m] = f4fma(a.x, w[0], acc[m]);
      acc[m] = f4fma(a.y, w[1], acc[m]);
      acc[m] = f4fma(a.z, w[2], acc[m]);
      acc[m] = f4fma(a.w, w[3], acc[m]);
    }
  }
  #pragma unroll
  for (int m = 0; m < 4; ++m) {
    float* pp = part + (size_t)(kt*32 + tb*4 + m)*N + col0;
    astore(pp + 0, acc[m].x); astore(pp + 1, acc[m].y);
    astore(pp + 2, acc[m].z); astore(pp + 3, acc[m].w);
  }
}

// ---------------- A-tile staging: 32 rows x 128 cols into LDS (pad 132) -----
// x is immutable -> plain vector loads; h/r/z are mutable -> agent loads.
__device__ __forceinline__ void stage_x(float* A, const float* __restrict__ src,
                                        size_t stride) {
  const int r = threadIdx.x >> 4, c0 = (threadIdx.x & 15) * 8;
  const float* s = src + (size_t)r*stride + c0;
  float4 v0 = *(const float4*)s, v1 = *(const float4*)(s + 4);
  *(float4*)(A + r*132 + c0)     = v0;
  *(float4*)(A + r*132 + c0 + 4) = v1;
}

__device__ __forceinline__ void stage_h(float* A, const float* src) {
  const int r = threadIdx.x >> 4, c0 = (threadIdx.x & 15) * 8;
  const float* s = src + (size_t)r*HD + c0;
  #pragma unroll
  for (int q = 0; q < 8; ++q) A[r*132 + c0 + q] = aload(s + q);
}

__device__ __forceinline__ void stage_rh(float* A, const float* rr,
                                         const float* hh) {
  const int r = threadIdx.x >> 4, c0 = (threadIdx.x & 15) * 8;
  const float* pr = rr + (size_t)r*HD + c0;
  const float* ph = hh + (size_t)r*HD + c0;
  #pragma unroll
  for (int q = 0; q < 8; ++q) A[r*132 + c0 + q] = aload(pr + q) * aload(ph + q);
}

__device__ __forceinline__ float sigmf(float v) { return 1.f / (1.f + expf(-v)); }

// ---------------- main persistent kernel ------------------------------------
__global__ __launch_bounds__(NTHR) void gru_main(GP p) {
  __shared__ float A[32*132];
  const int tid = threadIdx.x, wg = blockIdx.x;
  unsigned gen = 0;

  { int gt = wg*NTHR + tid;              // zero both parities of h0,h1 (131072)
    if (gt < 65536) astore(&p.h0buf[gt], 0.f); else astore(&p.h1buf[gt - 65536], 0.f); }
  gridbar(p, &gen);

  for (int i = 0; i < SS + 2; ++i) {
    const int a = i, s = i - 1, c = i - 2;
    const bool va = (a < SS), vs = (s >= 0 && s < SS), vc = (c >= 0 && c < SS);
    const float* h0_prev  = p.h0buf + (size_t)((i - 1) & 1) * 32768;  // h0(i-1)
    float*       h0_cur   = p.h0buf + (size_t)(i & 1) * 32768;        // h0(i) dest
    const float* h1_prev2 = p.h1buf + (size_t)(i & 1) * 32768;        // h1(i-2)
    float*       h1_w     = p.h1buf + (size_t)((i - 1) & 1) * 32768;  // h1(i-1) dest

    // ===== S1: G_zr0(a) [96 units] | G_zr1(s) [128 units] ====================
    if (wg < 96) { if (va) {
        const int kt = wg >> 3, jt = wg & 7;
        if (kt < 4) stage_x(A, p.x + (size_t)a*ID + kt*128, (size_t)SS*ID);
        else        stage_h(A, h0_prev + (kt*128 - 512));
        __syncthreads();
        gemm_unit(p.wt_zr0, 2048, kt, jt, A, p.p_zr0);
    }} else if (wg < 224) { if (vs) {
        const int u = wg - 96, kt = u >> 3, jt = u & 7;
        if (kt < 8) stage_h(A, h0_prev + kt*128);
        else        stage_h(A, h1_prev2 + (kt*128 - 1024));
        __syncthreads();
        gemm_unit(p.wt_zr1, 2048, kt, jt, A, p.p_zr1);
    }}
    gridbar(p, &gen);

    // ===== S2: R_zr0(a) | R_zr1(s) ==========================================
    { const int o = wg*NTHR + tid;
      if (o < 65536) { if (va) {
          const int b = o >> 11, col = o & 2047;
          float v = (col < 1024) ? p.bxz0[col] : p.bxr0[col - 1024];
          #pragma unroll
          for (int kt = 0; kt < 12; ++kt) v += aload(&p.p_zr0[(size_t)(kt*32 + b)*2048 + col]);
          const float sg = sigmf(v);
          if (col < 1024) astore(&p.z0[b*HD + col], sg); else astore(&p.r0[b*HD + col - 1024], sg);
      }} else { if (vs) {
          const int o2 = o - 65536, b = o2 >> 11, col = o2 & 2047;
          float v = (col < 1024) ? p.bxz1[col] : p.bxr1[col - 1024];
          #pragma unroll
          for (int kt = 0; kt < 16; ++kt) v += aload(&p.p_zr1[(size_t)(kt*32 + b)*2048 + col]);
          const float sg = sigmf(v);
          if (col < 1024) astore(&p.z1[b*HD + col], sg); else astore(&p.r1[b*HD + col - 1024], sg);
      }}}
    gridbar(p, &gen);

    // ===== S3: G_g0(a) [48] | G_g1(s) [64] | G_y(c) [16] =====================
    if (wg < 48) { if (va) {
        const int kt = wg >> 2, jt = wg & 3;
        if (kt < 4) stage_x(A, p.x + (size_t)a*ID + kt*128, (size_t)SS*ID);
        else        stage_rh(A, p.r0 + (kt*128 - 512), h0_prev + (kt*128 - 512));
        __syncthreads();
        gemm_unit(p.wt_g0, 1024, kt, jt, A, p.p_g0);
    }} else if (wg < 112) { if (vs) {
        const int u = wg - 48, kt = u >> 2, jt = u & 3;
        if (kt < 8) stage_h(A, h0_prev + kt*128);
        else        stage_rh(A, p.r1 + (kt*128 - 1024), h1_prev2 + (kt*128 - 1024));
        __syncthreads();
        gemm_unit(p.wt_g1, 1024, kt, jt, A, p.p_g1);
    }} else if (wg < 128) { if (vc) {
        const int u = wg - 112, kt = u >> 1, jt = u & 1;
        stage_h(A, h1_prev2 + kt*128);
        __syncthreads();
        gemm_unit(p.wt_y, 512, kt, jt, A, p.p_y);
    }}
    gridbar(p, &gen);

    // ===== S4: R_g0(a)->h0 | R_g1(s)->h1 | R_y(c)->out ======================
    { const int o = wg*NTHR + tid;
      if (o < 32768) { if (va) {
          const int b = o >> 10, j = o & 1023;
          float v = p.bxg0[j];
          #pragma unroll
          for (int kt = 0; kt < 12; ++kt) v += aload(&p.p_g0[(size_t)(kt*32 + b)*1024 + j]);
          const float g = tanhf(v);
          const float z = aload(&p.z0[o]);
          const float ho = aload(&h0_prev[o]);
          astore(&h0_cur[o], z*ho + (1.f - z)*g);
      }} else if (o < 65536) { if (vs) {
          const int o2 = o - 32768, b = o2 >> 10, j = o2 & 1023;
          float v = p.bxg1[j];
          #pragma unroll
          for (int kt = 0; kt < 16; ++kt) v += aload(&p.p_g1[(size_t)(kt*32 + b)*1024 + j]);
          const float g = tanhf(v);
          const float z = aload(&p.z1[o2]);
          const float ho = aload(&h1_prev2[o2]);
          astore(&h1_w[o2], z*ho + (1.f - z)*g);
      }} else if (o < 81920) { if (vc) {
          const int o2 = o - 65536, b = o2 >> 9, col = o2 & 511;
          float v = p.bhy[col];
          #pragma unroll
          for (int kt = 0; kt < 8; ++kt) v += aload(&p.p_y[(size_t)(kt*32 + b)*512 + col]);
          p.out[(size_t)b*(SS*OD) + (size_t)c*OD + col] = v;   // plain: kernel-end flush
      }}}
    gridbar(p, &gen);
  }

  // final hidden state: h0(511), h1(511) both live in parity-1 buffers
  { const int o = wg*NTHR + tid;
    if (o < 65536) {
      const int b = o >> 11, r2 = o & 2047, l = r2 >> 10, h = r2 & 1023;
      const float* hb = (l ? p.h1buf : p.h0buf) + 32768;
      p.out[OUT_HID_OFF + (size_t)b*2048 + l*1024 + h] = aload(&hb[b*HD + h]);
    } }
}

// ---------------- host launch ------------------------------------------------
extern "C" void kernel_launch(void* const* d_in, const int* in_sizes, int n_in,
                              void* d_out, int out_size, void* d_ws, size_t ws_size,
                              hipStream_t stream) {
  GP P;
  P.x    = (const float*)d_in[0];
  P.Wxz0 = (const float*)d_in[1];  P.bxz0 = (const float*)d_in[2];  P.Whz0 = (const float*)d_in[3];
  P.Wxr0 = (const float*)d_in[4];  P.bxr0 = (const float*)d_in[5];  P.Whr0 = (const float*)d_in[6];
  P.Wxg0 = (const float*)d_in[7];  P.bxg0 = (const float*)d_in[8];  P.Whg0 = (const float*)d_in[9];
  P.Wxz1 = (const float*)d_in[10]; P.bxz1 = (const float*)d_in[11]; P.Whz1 = (const float*)d_in[12];
  P.Wxr1 = (const float*)d_in[13]; P.bxr1 = (const float*)d_in[14]; P.Whr1 = (const float*)d_in[15];
  P.Wxg1 = (const float*)d_in[16]; P.bxg1 = (const float*)d_in[17]; P.Whg1 = (const float*)d_in[18];
  P.Why  = (const float*)d_in[19]; P.bhy  = (const float*)d_in[20];
  P.out  = (float*)d_out;

  float* ws = (float*)d_ws;
  size_t off = 0;
  P.wt_zr0 = ws + off; off += WT_ZR0_SZ;
  P.wt_g0  = ws + off; off += WT_G0_SZ;
  P.wt_zr1 = ws + off; off += WT_ZR1_SZ;
  P.wt_g1  = ws + off; off += WT_G1_SZ;
  P.wt_y   = ws + off; off += WT_Y_SZ;
  P.p_zr0  = ws + off; off += P_ZR0_SZ;
  P.p_g0   = ws + off; off += P_G0_SZ;
  P.p_zr1  = ws + off; off += P_ZR1_SZ;
  P.p_g1   = ws + off; off += P_G1_SZ;
  P.p_y    = ws + off; off += P_Y_SZ;
  P.h0buf  = ws + off; off += 2*32768;
  P.h1buf  = ws + off; off += 2*32768;
  P.z0     = ws + off; off += 32768;
  P.r0     = ws + off; off += 32768;
  P.z1     = ws + off; off += 32768;
  P.r1     = ws + off; off += 32768;
  P.flags  = (unsigned*)(ws + off); off += NWG*FLAG_STRIDE;
  P.bar_gen = (unsigned*)(ws + off);

  hipMemsetAsync(P.flags, 0, (NWG*FLAG_STRIDE + 1)*sizeof(unsigned), stream);

  transp<<<dim3(2816), dim3(256), 0, stream>>>(P);

  void* args[] = { &P };
  hipLaunchCooperativeKernel((const void*)gru_main,
                             dim3(NWG), dim3(NTHR), args, 0, stream);
}

// Round 4
// 30334.235 us; speedup vs baseline: 4.7587x; 1.1180x over previous
//
#include <hip/hip_runtime.h>

#define SS 512
#define NWG 32
#define NTHR 512
#define FLAG_STRIDE 32
#define OUT_HID_OFF 8388608   // 32*512*512

typedef _Float16 fh8 __attribute__((ext_vector_type(8)));
typedef float f32x4 __attribute__((ext_vector_type(4)));

struct GP {
  const float *x;
  const float *Wxz0,*bxz0,*Whz0,*Wxr0,*bxr0,*Whr0,*Wxg0,*bxg0,*Whg0;
  const float *Wxz1,*bxz1,*Whz1,*Wxr1,*bxr1,*Whr1,*Wxg1,*bxg1,*Whg1;
  const float *Why,*bhy;
  float *out;
  _Float16 *xb;                       // [32][512][512] f16
  _Float16 *wzr0,*wzr1,*wg0,*wg1,*wy; // packed B-fragment order
  float *h0f,*h1f;                    // [2][32][1024] f32
  _Float16 *h0h,*h1h;                 // [2][32][1024] f16
  float *z0,*r0,*z1,*r1;              // [32][1024] f32
  unsigned *flags;                    // [NWG][FLAG_STRIDE]
};

// ---------- agent-scope scalar accessors (MALL-coherent) ----------
__device__ __forceinline__ float aload(const float* p) {
  return __hip_atomic_load(p, __ATOMIC_RELAXED, __HIP_MEMORY_SCOPE_AGENT);
}
__device__ __forceinline__ void astore(float* p, float v) {
  __hip_atomic_store(p, v, __ATOMIC_RELAXED, __HIP_MEMORY_SCOPE_AGENT);
}
// 16B bypass load (sc0 sc1: skip non-coherent L2s)
__device__ __forceinline__ void bload(uint4& d, const void* p) {
  asm volatile("global_load_dwordx4 %0, %1, off sc0 sc1"
               : "=&v"(d) : "v"(p) : "memory");
}
// f16 bypass store
__device__ __forceinline__ void sstore(_Float16* pd, float v) {
  _Float16 h = (_Float16)v;
  unsigned short u; __builtin_memcpy(&u, &h, 2);
  asm volatile("global_store_short %0, %1, off sc0 sc1"
               :: "v"(pd), "v"((unsigned)u) : "memory");
}
__device__ __forceinline__ float uf(unsigned u){ union{unsigned u;float f;}c; c.u=u; return c.f; }
__device__ __forceinline__ float sigmf(float v){ return 1.f/(1.f+__expf(-v)); }

// ---------- one-time pack: weights -> f16 B-fragment order, x -> f16 ----------
// b_frag[lane][j] = W[n = ntg*16 + (lane&15)][k = kc*32 + (lane>>4)*8 + j]
// dst offset = ((ntg*KC + kc)*64 + lane)*8
__global__ __launch_bounds__(256) void pack(GP p) {
  const long gid = (long)blockIdx.x*256 + threadIdx.x;
  if (gid < 1441792) {
    long u; int KC; _Float16* dst;
    if (gid < 393216)       { u=gid;         KC=48; dst=p.wzr0; }
    else if (gid < 917504)  { u=gid-393216;  KC=64; dst=p.wzr1; }
    else if (gid < 1114112) { u=gid-917504;  KC=48; dst=p.wg0;  }
    else if (gid < 1376256) { u=gid-1114112; KC=64; dst=p.wg1;  }
    else                    { u=gid-1376256; KC=32; dst=p.wy;   }
    const int per = KC*64;
    const int ntg = (int)(u/per); const int r = (int)(u%per);
    const int kc = r>>6, lane = r&63;
    const int n = ntg*16 + (lane&15);
    const int k = kc*32 + ((lane>>4)<<3);
    const float* src;
    if (gid < 393216) {                     // zr0: K = 512(x)+1024(h), N=2048 (z|r)
      int g = n>>10, nn = n&1023;
      src = (k<512) ? ((g?p.Wxr0:p.Wxz0) + (size_t)nn*512 + k)
                    : ((g?p.Whr0:p.Whz0) + (size_t)nn*1024 + (k-512));
    } else if (gid < 917504) {              // zr1: K = 1024+1024
      int g = n>>10, nn = n&1023;
      src = (k<1024) ? ((g?p.Wxr1:p.Wxz1) + (size_t)nn*1024 + k)
                     : ((g?p.Whr1:p.Whz1) + (size_t)nn*1024 + (k-1024));
    } else if (gid < 1114112) {             // g0
      src = (k<512) ? (p.Wxg0 + (size_t)n*512 + k)
                    : (p.Whg0 + (size_t)n*1024 + (k-512));
    } else if (gid < 1376256) {             // g1
      src = (k<1024) ? (p.Wxg1 + (size_t)n*1024 + k)
                     : (p.Whg1 + (size_t)n*1024 + (k-1024));
    } else {                                // y
      src = p.Why + (size_t)n*1024 + k;
    }
    float4 f0 = *(const float4*)src, f1 = *(const float4*)(src+4);
    fh8 h;
    h[0]=(_Float16)f0.x; h[1]=(_Float16)f0.y; h[2]=(_Float16)f0.z; h[3]=(_Float16)f0.w;
    h[4]=(_Float16)f1.x; h[5]=(_Float16)f1.y; h[6]=(_Float16)f1.z; h[7]=(_Float16)f1.w;
    *(fh8*)(dst + u*8) = h;
  } else if (gid < 2490368) {
    const long e = (gid - 1441792)*8;
    float4 f0 = *(const float4*)(p.x + e), f1 = *(const float4*)(p.x + e + 4);
    fh8 h;
    h[0]=(_Float16)f0.x; h[1]=(_Float16)f0.y; h[2]=(_Float16)f0.z; h[3]=(_Float16)f0.w;
    h[4]=(_Float16)f1.x; h[5]=(_Float16)f1.y; h[6]=(_Float16)f1.z; h[7]=(_Float16)f1.w;
    *(fh8*)(p.xb + e) = h;
  }
}

// ---------- all-poll-all grid barrier ----------
__device__ __forceinline__ void gridbar(unsigned* flags, unsigned g) {
  asm volatile("s_waitcnt vmcnt(0) lgkmcnt(0)" ::: "memory");
  __syncthreads();
  if (threadIdx.x == 0)
    __hip_atomic_store(flags + (size_t)blockIdx.x*FLAG_STRIDE, g,
                       __ATOMIC_RELEASE, __HIP_MEMORY_SCOPE_AGENT);
  if (threadIdx.x < NWG) {
    const unsigned* f = flags + (size_t)threadIdx.x*FLAG_STRIDE;
    while (__hip_atomic_load(f, __ATOMIC_RELAXED, __HIP_MEMORY_SCOPE_AGENT) < g)
      __builtin_amdgcn_s_sleep(1);
  }
  asm volatile("" ::: "memory");
  __syncthreads();
}

// ---------- staging: 32 rows x 512 k f16 slice into XOR-swizzled LDS ----------
// LDS layout: byte = row*1024 + (kbyte ^ ((row&15)<<4))   (conflict-free b128 reads)
struct St16 { uint4 v[16]; };
struct Sl { int mode; const void* pa; const void* pb; };  // 0=f16 bypass, 1=f16 plain(xb), 2=r*h f32

__device__ __forceinline__ void issue_sl(St16& R, Sl s, int t) {
  const int row = t>>4, seg = t&15;
  if (s.mode == 2) {
    const char* rp = (const char*)((const float*)s.pa + (size_t)row*1024) + seg*128;
    const char* hp = (const char*)((const float*)s.pb + (size_t)row*1024) + seg*128;
    #pragma unroll
    for (int q=0;q<8;++q){ bload(R.v[q], rp + q*16); bload(R.v[q+8], hp + q*16); }
  } else if (s.mode == 1) {
    const uint4* sp = (const uint4*)((const _Float16*)s.pa + (size_t)row*262144 + seg*32);
    R.v[0]=sp[0]; R.v[1]=sp[1]; R.v[2]=sp[2]; R.v[3]=sp[3];
  } else {
    const char* sp = (const char*)((const _Float16*)s.pa + (size_t)row*1024) + seg*64;
    bload(R.v[0], sp); bload(R.v[1], sp+16); bload(R.v[2], sp+32); bload(R.v[3], sp+48);
  }
}

__device__ __forceinline__ void commit_sl(const St16& R, Sl s, _Float16* As, int t) {
  asm volatile("s_waitcnt vmcnt(0)" ::: "memory");
  __builtin_amdgcn_sched_barrier(0);
  const int row = t>>4, seg = t&15, key = (row&15)<<4;
  char* d = (char*)As + row*1024;
  if (s.mode == 2) {
    #pragma unroll
    for (int c2=0;c2<4;++c2) {
      uint4 ra = R.v[c2*2], rb = R.v[c2*2+1], ha = R.v[8+c2*2], hb = R.v[9+c2*2];
      fh8 o;
      o[0]=(_Float16)(uf(ra.x)*uf(ha.x)); o[1]=(_Float16)(uf(ra.y)*uf(ha.y));
      o[2]=(_Float16)(uf(ra.z)*uf(ha.z)); o[3]=(_Float16)(uf(ra.w)*uf(ha.w));
      o[4]=(_Float16)(uf(rb.x)*uf(hb.x)); o[5]=(_Float16)(uf(rb.y)*uf(hb.y));
      o[6]=(_Float16)(uf(rb.z)*uf(hb.z)); o[7]=(_Float16)(uf(rb.w)*uf(hb.w));
      *(fh8*)(d + ((seg*64 + c2*16) ^ key)) = o;
    }
  } else {
    *(uint4*)(d + ((seg*64 +  0) ^ key)) = R.v[0];
    *(uint4*)(d + ((seg*64 + 16) ^ key)) = R.v[1];
    *(uint4*)(d + ((seg*64 + 32) ^ key)) = R.v[2];
    *(uint4*)(d + ((seg*64 + 48) ^ key)) = R.v[3];
  }
}

// ---------- MFMA over one staged 512-k slice: wave owns n-tile ntg, both m-tiles ----------
__device__ __forceinline__ void compute_slice(const _Float16* As, const _Float16* wb,
                                              f32x4& acc0, f32x4& acc1, int l) {
  const int lrow = l & 15, key = lrow << 4, lg16 = (l >> 4) << 4;
  const char* ab = (const char*)As + lrow*1024;
  #pragma unroll 8
  for (int kk = 0; kk < 16; ++kk) {
    const int off = (kk*64 + lg16) ^ key;
    fh8 a0 = *(const fh8*)(ab + off);            // rows 0..15
    fh8 a1 = *(const fh8*)(ab + 16384 + off);    // rows 16..31
    fh8 b  = *(const fh8*)(wb + kk*512);
    acc0 = __builtin_amdgcn_mfma_f32_16x16x32_f16(a0, b, acc0, 0, 0, 0);
    acc1 = __builtin_amdgcn_mfma_f32_16x16x32_f16(a1, b, acc1, 0, 0, 0);
  }
}

__device__ __forceinline__ void run_unit(const Sl* sl, int nsl, const _Float16* wpk,
    int KC, int ntg, _Float16* As, f32x4& acc0, f32x4& acc1) {
  const int t = threadIdx.x, l = t & 63;
  St16 R;
  issue_sl(R, sl[0], t);
  commit_sl(R, sl[0], As, t);
  __syncthreads();
  for (int j = 0; j < nsl; ++j) {
    if (j+1 < nsl) issue_sl(R, sl[j+1], t);      // prefetch next slice into regs
    const _Float16* wb = wpk + ((size_t)ntg*KC + j*16)*512 + (size_t)l*8;
    compute_slice(As, wb, acc0, acc1, l);
    __syncthreads();
    if (j+1 < nsl) { commit_sl(R, sl[j+1], As, t); __syncthreads(); }
  }
}

// ---------- epilogues (C/D: col = lane&15, row b = (lane>>4)*4 + q) ----------
__device__ __forceinline__ void epi_zr(const f32x4& a0, const f32x4& a1, int ntg, int l,
    const float* bz, const float* br, float* zA, float* rA) {
  const int col = ntg*16 + (l&15);
  const int gate = col >> 10, cc = col & 1023;
  const float bias = gate ? br[cc] : bz[cc];
  float* dst = (gate ? rA : zA) + cc;
  const int brow = (l>>4)<<2;
  #pragma unroll
  for (int q=0;q<4;++q) {
    astore(dst + (size_t)(brow+q)*1024,    sigmf(a0[q]+bias));
    astore(dst + (size_t)(brow+q+16)*1024, sigmf(a1[q]+bias));
  }
}
__device__ __forceinline__ void epi_g(const f32x4& a0, const f32x4& a1, int ntg, int l,
    const float* bg, const float* zA, const float* hOld, float* hNewF, _Float16* hNewH) {
  const int col = ntg*16 + (l&15);
  const float bias = bg[col];
  const int brow = (l>>4)<<2;
  #pragma unroll
  for (int q=0;q<4;++q) {
    { const int b = brow+q;
      const float g = tanhf(a0[q]+bias);
      const float z = aload(zA + (size_t)b*1024 + col);
      const float ho = aload(hOld + (size_t)b*1024 + col);
      const float hn = z*ho + (1.f-z)*g;
      astore(hNewF + (size_t)b*1024 + col, hn);
      sstore(hNewH + (size_t)b*1024 + col, hn); }
    { const int b = brow+q+16;
      const float g = tanhf(a1[q]+bias);
      const float z = aload(zA + (size_t)b*1024 + col);
      const float ho = aload(hOld + (size_t)b*1024 + col);
      const float hn = z*ho + (1.f-z)*g;
      astore(hNewF + (size_t)b*1024 + col, hn);
      sstore(hNewH + (size_t)b*1024 + col, hn); }
  }
}

// ---------- main persistent kernel ----------
__global__ __launch_bounds__(NTHR) void gru_main(GP p) {
  __shared__ _Float16 As[32*512];
  const int tid = threadIdx.x, wg = blockIdx.x;
  const int wid = tid >> 6, l = tid & 63;
  unsigned gen = 0;

  for (int i = 0; i < SS + 2; ++i) {
    const int a = i, s = i - 1, c = i - 2;
    const bool va = a < SS, vs = (s >= 0) && (s < SS), vc = (c >= 0);
    const int pOld = (i + 1) & 1, pNew = i & 1;
    const float*    h0f_old  = p.h0f + pOld*32768;   // h0(i-1)
    float*          h0f_new  = p.h0f + pNew*32768;   // h0(i)
    const _Float16* h0h_old  = p.h0h + pOld*32768;
    _Float16*       h0h_new  = p.h0h + pNew*32768;
    const float*    h1f_old2 = p.h1f + pNew*32768;   // h1(i-2)
    float*          h1f_new  = p.h1f + pOld*32768;   // h1(i-1)
    const _Float16* h1h_old2 = p.h1h + pNew*32768;
    _Float16*       h1h_new  = p.h1h + pOld*32768;

    // ===== S_A: zr0(a) [wg 0-15] | zr1(s) [wg 16-31] =====
    if (wg < 16) {
      if (va) {
        Sl sl[3] = { {1, p.xb + (size_t)a*512, nullptr},
                     {0, h0h_old, nullptr},
                     {0, h0h_old + 512, nullptr} };
        f32x4 acc0 = {0.f,0.f,0.f,0.f}, acc1 = {0.f,0.f,0.f,0.f};
        const int ntg = wg*8 + wid;
        run_unit(sl, 3, p.wzr0, 48, ntg, As, acc0, acc1);
        epi_zr(acc0, acc1, ntg, l, p.bxz0, p.bxr0, p.z0, p.r0);
      }
    } else {
      if (vs) {
        Sl sl[4] = { {0, h0h_old, nullptr}, {0, h0h_old + 512, nullptr},
                     {0, h1h_old2, nullptr}, {0, h1h_old2 + 512, nullptr} };
        f32x4 acc0 = {0.f,0.f,0.f,0.f}, acc1 = {0.f,0.f,0.f,0.f};
        const int ntg = (wg-16)*8 + wid;
        run_unit(sl, 4, p.wzr1, 64, ntg, As, acc0, acc1);
        epi_zr(acc0, acc1, ntg, l, p.bxz1, p.bxr1, p.z1, p.r1);
      }
    }
    gridbar(p.flags, ++gen);

    // ===== S_B: g0+h0(a) [wg 0-7] | g1+h1(s) [wg 8-15] | y(c) [wg 16-19] =====
    if (wg < 8) {
      if (va) {
        Sl sl[3] = { {1, p.xb + (size_t)a*512, nullptr},
                     {2, p.r0, h0f_old},
                     {2, p.r0 + 512, h0f_old + 512} };
        f32x4 acc0 = {0.f,0.f,0.f,0.f}, acc1 = {0.f,0.f,0.f,0.f};
        const int ntg = wg*8 + wid;
        run_unit(sl, 3, p.wg0, 48, ntg, As, acc0, acc1);
        epi_g(acc0, acc1, ntg, l, p.bxg0, p.z0, h0f_old, h0f_new, h0h_new);
      }
    } else if (wg < 16) {
      if (vs) {
        Sl sl[4] = { {0, h0h_old, nullptr}, {0, h0h_old + 512, nullptr},
                     {2, p.r1, h1f_old2}, {2, p.r1 + 512, h1f_old2 + 512} };
        f32x4 acc0 = {0.f,0.f,0.f,0.f}, acc1 = {0.f,0.f,0.f,0.f};
        const int ntg = (wg-8)*8 + wid;
        run_unit(sl, 4, p.wg1, 64, ntg, As, acc0, acc1);
        epi_g(acc0, acc1, ntg, l, p.bxg1, p.z1, h1f_old2, h1f_new, h1h_new);
      }
    } else if (wg < 20) {
      if (vc) {
        Sl sl[2] = { {0, h1h_old2, nullptr}, {0, h1h_old2 + 512, nullptr} };
        f32x4 acc0 = {0.f,0.f,0.f,0.f}, acc1 = {0.f,0.f,0.f,0.f};
        const int ntg = (wg-16)*8 + wid;
        run_unit(sl, 2, p.wy, 32, ntg, As, acc0, acc1);
        const int col = ntg*16 + (l&15);
        const float bias = p.bhy[col];
        const int brow = (l>>4)<<2;
        #pragma unroll
        for (int q=0;q<4;++q) {
          p.out[(size_t)(brow+q)*262144    + (size_t)c*512 + col] = acc0[q] + bias;
          p.out[(size_t)(brow+q+16)*262144 + (size_t)c*512 + col] = acc1[q] + bias;
        }
      }
    }
    gridbar(p.flags, ++gen);
  }

  // final hidden_state (B, 2, H): h0(511), h1(511) live in parity-1
  {
    const int o = wg*NTHR + tid;
    #pragma unroll
    for (int q=0;q<4;++q) {
      const int e = o + q*16384;
      const int b = e >> 11, r2 = e & 2047, lay = r2 >> 10, hcol = r2 & 1023;
      const float* hb = (lay ? p.h1f : p.h0f) + 32768 + b*1024 + hcol;
      p.out[OUT_HID_OFF + (size_t)b*2048 + (size_t)lay*1024 + hcol] = aload(hb);
    }
  }
}

// ---------- host ----------
extern "C" void kernel_launch(void* const* d_in, const int* in_sizes, int n_in,
                              void* d_out, int out_size, void* d_ws, size_t ws_size,
                              hipStream_t stream) {
  GP P;
  P.x    = (const float*)d_in[0];
  P.Wxz0 = (const float*)d_in[1];  P.bxz0 = (const float*)d_in[2];  P.Whz0 = (const float*)d_in[3];
  P.Wxr0 = (const float*)d_in[4];  P.bxr0 = (const float*)d_in[5];  P.Whr0 = (const float*)d_in[6];
  P.Wxg0 = (const float*)d_in[7];  P.bxg0 = (const float*)d_in[8];  P.Whg0 = (const float*)d_in[9];
  P.Wxz1 = (const float*)d_in[10]; P.bxz1 = (const float*)d_in[11]; P.Whz1 = (const float*)d_in[12];
  P.Wxr1 = (const float*)d_in[13]; P.bxr1 = (const float*)d_in[14]; P.Whr1 = (const float*)d_in[15];
  P.Wxg1 = (const float*)d_in[16]; P.bxg1 = (const float*)d_in[17]; P.Whg1 = (const float*)d_in[18];
  P.Why  = (const float*)d_in[19]; P.bhy  = (const float*)d_in[20];
  P.out  = (float*)d_out;

  char* ws = (char*)d_ws;
  P.xb   = (_Float16*)(ws + 0);           // 16777216 B
  P.wzr0 = (_Float16*)(ws + 16777216);    // 6291456
  P.wzr1 = (_Float16*)(ws + 23068672);    // 8388608
  P.wg0  = (_Float16*)(ws + 31457280);    // 3145728
  P.wg1  = (_Float16*)(ws + 34603008);    // 4194304
  P.wy   = (_Float16*)(ws + 38797312);    // 1048576
  P.h0f  = (float*)   (ws + 39845888);    // 262144
  P.h1f  = (float*)   (ws + 40108032);    // 262144
  P.h0h  = (_Float16*)(ws + 40370176);    // 131072
  P.h1h  = (_Float16*)(ws + 40501248);    // 131072
  P.z0   = (float*)   (ws + 40632320);    // 131072
  P.r0   = (float*)   (ws + 40763392);    // 131072
  P.z1   = (float*)   (ws + 40894464);    // 131072
  P.r1   = (float*)   (ws + 41025536);    // 131072
  P.flags= (unsigned*)(ws + 41156608);    // 4096

  // zero h (both parities), z/r, flags in one shot
  hipMemsetAsync(ws + 39845888, 0, 41160704 - 39845888, stream);

  pack<<<dim3(9728), dim3(256), 0, stream>>>(P);

  void* args[] = { &P };
  hipLaunchCooperativeKernel((const void*)gru_main,
                             dim3(NWG), dim3(NTHR), args, 0, stream);
}

// Round 5
// 24861.549 us; speedup vs baseline: 5.8063x; 1.2201x over previous
//
#include <hip/hip_runtime.h>

#define SS 512
#define NWG 32
#define NTHR 512
#define FLAG_STRIDE 32
#define OUT_HID_OFF 8388608   // 32*512*512

typedef _Float16 fh8 __attribute__((ext_vector_type(8)));
typedef float f32x4 __attribute__((ext_vector_type(4)));

struct GP {
  const float *x;
  const float *Wxz0,*bxz0,*Whz0,*Wxr0,*bxr0,*Whr0,*Wxg0,*bxg0,*Whg0;
  const float *Wxz1,*bxz1,*Whz1,*Wxr1,*bxr1,*Whr1,*Wxg1,*bxg1,*Whg1;
  const float *Why,*bhy;
  float *out;
  _Float16 *xb;                       // [32][512][512] f16 (b-major)
  _Float16 *wzr0,*wzr1,*wg0,*wg1,*wy; // packed B-fragment order
  float *h0f,*h1f;                    // [2][32][1024] f32
  _Float16 *h0h,*h1h;                 // [2][32][1024] f16
  float *z0,*z1;                      // [32][1024] f32
  _Float16 *r0h,*r1h;                 // [32][1024] f16
  unsigned *flags;                    // [NWG][FLAG_STRIDE]
};

// ---------- accessors ----------
__device__ __forceinline__ void astore(float* p, float v) {
  __hip_atomic_store(p, v, __ATOMIC_RELAXED, __HIP_MEMORY_SCOPE_AGENT);
}
__device__ __forceinline__ void bload(uint4& d, const void* p) {
  asm volatile("global_load_dwordx4 %0, %1, off sc0 sc1"
               : "=&v"(d) : "v"(p) : "memory");
}
__device__ __forceinline__ void bload1(float& d, const float* p) {
  asm volatile("global_load_dword %0, %1, off sc0 sc1"
               : "=&v"(d) : "v"(p) : "memory");
}
__device__ __forceinline__ void sstore(_Float16* pd, float v) {
  _Float16 h = (_Float16)v;
  unsigned short u; __builtin_memcpy(&u, &h, 2);
  asm volatile("global_store_short %0, %1, off sc0 sc1"
               :: "v"(pd), "v"((unsigned)u) : "memory");
}
__device__ __forceinline__ fh8 u2h(uint4 v){ fh8 r; __builtin_memcpy(&r, &v, 16); return r; }
__device__ __forceinline__ uint4 h2u(fh8 v){ uint4 r; __builtin_memcpy(&r, &v, 16); return r; }
__device__ __forceinline__ float sigmf(float v){ return 1.f/(1.f+__expf(-v)); }

// ---------- one-time pack: weights -> f16 B-fragment order, x -> f16 ----------
// b_frag[lane][j] = W[n = ntg*16 + (lane&15)][k = kc*32 + (lane>>4)*8 + j]
__global__ __launch_bounds__(256) void pack(GP p) {
  const long gid = (long)blockIdx.x*256 + threadIdx.x;
  if (gid < 1441792) {
    long u; int KC; _Float16* dst;
    if (gid < 393216)       { u=gid;         KC=48; dst=p.wzr0; }
    else if (gid < 917504)  { u=gid-393216;  KC=64; dst=p.wzr1; }
    else if (gid < 1114112) { u=gid-917504;  KC=48; dst=p.wg0;  }
    else if (gid < 1376256) { u=gid-1114112; KC=64; dst=p.wg1;  }
    else                    { u=gid-1376256; KC=32; dst=p.wy;   }
    const int per = KC*64;
    const int ntg = (int)(u/per); const int r = (int)(u%per);
    const int kc = r>>6, lane = r&63;
    const int n = ntg*16 + (lane&15);
    const int k = kc*32 + ((lane>>4)<<3);
    const float* src;
    if (gid < 393216) {
      int g = n>>10, nn = n&1023;
      src = (k<512) ? ((g?p.Wxr0:p.Wxz0) + (size_t)nn*512 + k)
                    : ((g?p.Whr0:p.Whz0) + (size_t)nn*1024 + (k-512));
    } else if (gid < 917504) {
      int g = n>>10, nn = n&1023;
      src = (k<1024) ? ((g?p.Wxr1:p.Wxz1) + (size_t)nn*1024 + k)
                     : ((g?p.Whr1:p.Whz1) + (size_t)nn*1024 + (k-1024));
    } else if (gid < 1114112) {
      src = (k<512) ? (p.Wxg0 + (size_t)n*512 + k)
                    : (p.Whg0 + (size_t)n*1024 + (k-512));
    } else if (gid < 1376256) {
      src = (k<1024) ? (p.Wxg1 + (size_t)n*1024 + k)
                     : (p.Whg1 + (size_t)n*1024 + (k-1024));
    } else {
      src = p.Why + (size_t)n*1024 + k;
    }
    float4 f0 = *(const float4*)src, f1 = *(const float4*)(src+4);
    fh8 h;
    h[0]=(_Float16)f0.x; h[1]=(_Float16)f0.y; h[2]=(_Float16)f0.z; h[3]=(_Float16)f0.w;
    h[4]=(_Float16)f1.x; h[5]=(_Float16)f1.y; h[6]=(_Float16)f1.z; h[7]=(_Float16)f1.w;
    *(fh8*)(dst + u*8) = h;
  } else if (gid < 2490368) {
    const long e = (gid - 1441792)*8;
    float4 f0 = *(const float4*)(p.x + e), f1 = *(const float4*)(p.x + e + 4);
    fh8 h;
    h[0]=(_Float16)f0.x; h[1]=(_Float16)f0.y; h[2]=(_Float16)f0.z; h[3]=(_Float16)f0.w;
    h[4]=(_Float16)f1.x; h[5]=(_Float16)f1.y; h[6]=(_Float16)f1.z; h[7]=(_Float16)f1.w;
    *(fh8*)(p.xb + e) = h;
  }
}

// ---------- all-poll-all grid barrier (relaxed flags; vmcnt drained first) ----------
__device__ __forceinline__ void gridbar(unsigned* flags, unsigned g) {
  asm volatile("s_waitcnt vmcnt(0) lgkmcnt(0)" ::: "memory");
  __syncthreads();
  if (threadIdx.x == 0)
    __hip_atomic_store(flags + (size_t)blockIdx.x*FLAG_STRIDE, g,
                       __ATOMIC_RELAXED, __HIP_MEMORY_SCOPE_AGENT);
  if (threadIdx.x < NWG) {
    const unsigned* f = flags + (size_t)threadIdx.x*FLAG_STRIDE;
    while (__hip_atomic_load(f, __ATOMIC_RELAXED, __HIP_MEMORY_SCOPE_AGENT) < g)
      __builtin_amdgcn_s_sleep(1);
  }
  asm volatile("" ::: "memory");
  __syncthreads();
}

// ---------- phase descriptors ----------
struct SegF { const _Float16* base; int rs; };     // f16 copy seg (512 k)
struct SegP { const _Float16* ra; const _Float16* ha; }; // r*h product seg (512 k, rs=1024)

// One phase: batched issue -> single vmcnt -> LDS commit -> sync -> MFMA sweep.
// LDS: byte(row,kb) = row*4096 + (kb ^ ((row&15)<<4)); panel K = (NF+NP)*512.
template<int NF, int NP, bool EPRE>
__device__ __forceinline__ void run_phase(const SegF* fs, const SegP* ps,
    const _Float16* wpk, int ntg, _Float16* As, f32x4& acc0, f32x4& acc1,
    const float* zsrc, const float* hsrc, float* zv, float* hv) {
  constexpr int NSL = NF + NP;
  constexpr int KC  = NSL * 16;
  const int t = threadIdx.x, l = t & 63;
  const int row = t >> 4, s16 = t & 15;

  uint4 Rf[NF ? NF*4 : 1];
  uint4 Ra[NP ? NP*4 : 1];
  uint4 Rh[NP ? NP*4 : 1];

  // ---- issue everything (one latency exposure) ----
  #pragma unroll
  for (int s = 0; s < NF; ++s) {
    const char* sp = (const char*)(fs[s].base + (size_t)row*fs[s].rs) + s16*64;
    #pragma unroll
    for (int q = 0; q < 4; ++q) bload(Rf[s*4+q], sp + q*16);
  }
  #pragma unroll
  for (int s = 0; s < NP; ++s) {
    const char* rp = (const char*)(ps[s].ra + (size_t)row*1024) + s16*64;
    const char* hp = (const char*)(ps[s].ha + (size_t)row*1024) + s16*64;
    #pragma unroll
    for (int q = 0; q < 4; ++q) { bload(Ra[s*4+q], rp + q*16); bload(Rh[s*4+q], hp + q*16); }
  }
  if constexpr (EPRE) {
    const int col = ntg*16 + (l&15), brow = (l>>4)<<2;
    #pragma unroll
    for (int q = 0; q < 4; ++q) {
      bload1(zv[q],   zsrc + (size_t)(brow+q)*1024 + col);
      bload1(zv[q+4], zsrc + (size_t)(brow+q+16)*1024 + col);
      bload1(hv[q],   hsrc + (size_t)(brow+q)*1024 + col);
      bload1(hv[q+4], hsrc + (size_t)(brow+q+16)*1024 + col);
    }
  }
  asm volatile("s_waitcnt vmcnt(0)" ::: "memory");
  __builtin_amdgcn_sched_barrier(0);

  // ---- commit to LDS ----
  const int key = (row & 15) << 4;
  char* d = (char*)As + row*4096;
  #pragma unroll
  for (int s = 0; s < NF; ++s) {
    const int kb0 = s*1024 + s16*64;
    #pragma unroll
    for (int q = 0; q < 4; ++q) *(uint4*)(d + ((kb0 + q*16) ^ key)) = Rf[s*4+q];
  }
  #pragma unroll
  for (int s = 0; s < NP; ++s) {
    const int kb0 = (NF+s)*1024 + s16*64;
    #pragma unroll
    for (int q = 0; q < 4; ++q) {
      fh8 o = u2h(Ra[s*4+q]) * u2h(Rh[s*4+q]);      // v_pk_mul_f16
      *(uint4*)(d + ((kb0 + q*16) ^ key)) = h2u(o);
    }
  }
  __syncthreads();

  // ---- MFMA sweep (weights: plain L2-cached loads) ----
  const int lrow = l & 15, key2 = lrow << 4, lg16 = (l >> 4) << 4;
  const char* ab = (const char*)As + lrow*4096;
  const _Float16* wb = wpk + (size_t)ntg*KC*512 + (size_t)l*8;
  #pragma unroll 8
  for (int kk = 0; kk < KC; ++kk) {
    const int off = (kk*64 + lg16) ^ key2;
    fh8 a0 = *(const fh8*)(ab + off);
    fh8 a1 = *(const fh8*)(ab + 16*4096 + off);
    fh8 b  = *(const fh8*)(wb + (size_t)kk*512);
    acc0 = __builtin_amdgcn_mfma_f32_16x16x32_f16(a0, b, acc0, 0, 0, 0);
    acc1 = __builtin_amdgcn_mfma_f32_16x16x32_f16(a1, b, acc1, 0, 0, 0);
  }
}

// ---------- epilogues (C/D: col = lane&15, row b = (lane>>4)*4 + q) ----------
__device__ __forceinline__ void epi_zr(const f32x4& a0, const f32x4& a1, int ntg, int l,
    const float* bz, const float* br, float* zbuf, _Float16* rbuf) {
  const int col = ntg*16 + (l&15);
  const int gate = col >> 10, cc = col & 1023;
  const float bias = gate ? br[cc] : bz[cc];
  const int brow = (l>>4)<<2;
  #pragma unroll
  for (int q = 0; q < 4; ++q) {
    const float v0 = sigmf(a0[q]+bias), v1 = sigmf(a1[q]+bias);
    if (gate) {
      sstore(rbuf + (size_t)(brow+q)*1024 + cc, v0);
      sstore(rbuf + (size_t)(brow+q+16)*1024 + cc, v1);
    } else {
      astore(zbuf + (size_t)(brow+q)*1024 + cc, v0);
      astore(zbuf + (size_t)(brow+q+16)*1024 + cc, v1);
    }
  }
}
__device__ __forceinline__ void epi_g(const f32x4& a0, const f32x4& a1, int ntg, int l,
    const float* bg, const float* zv, const float* hv, float* hNewF, _Float16* hNewH) {
  const int col = ntg*16 + (l&15);
  const float bias = bg[col];
  const int brow = (l>>4)<<2;
  #pragma unroll
  for (int q = 0; q < 4; ++q) {
    { const float g = tanhf(a0[q]+bias);
      const float hn = zv[q]*hv[q] + (1.f-zv[q])*g;
      astore(hNewF + (size_t)(brow+q)*1024 + col, hn);
      sstore(hNewH + (size_t)(brow+q)*1024 + col, hn); }
    { const float g = tanhf(a1[q]+bias);
      const float hn = zv[q+4]*hv[q+4] + (1.f-zv[q+4])*g;
      astore(hNewF + (size_t)(brow+q+16)*1024 + col, hn);
      sstore(hNewH + (size_t)(brow+q+16)*1024 + col, hn); }
  }
}

// ---------- main persistent kernel ----------
__global__ __launch_bounds__(NTHR) void gru_main(GP p) {
  __shared__ _Float16 As[32*2048];   // 128 KiB A-panel
  const int tid = threadIdx.x, wg = blockIdx.x;
  const int wid = tid >> 6, l = tid & 63;
  unsigned gen = 0;
  float zv[8], hv[8];

  for (int i = 0; i < SS + 2; ++i) {
    const int a = i, s = i - 1, c = i - 2;
    const bool va = a < SS, vs = (s >= 0) && (s < SS), vc = (c >= 0);
    const int pOld = (i + 1) & 1, pNew = i & 1;
    const float*    h0f_old  = p.h0f + pOld*32768;   // h0(i-1)
    float*          h0f_new  = p.h0f + pNew*32768;   // h0(i)
    const _Float16* h0h_old  = p.h0h + pOld*32768;
    _Float16*       h0h_new  = p.h0h + pNew*32768;
    const float*    h1f_old2 = p.h1f + pNew*32768;   // h1(i-2)
    float*          h1f_new  = p.h1f + pOld*32768;   // h1(i-1)
    const _Float16* h1h_old2 = p.h1h + pNew*32768;
    _Float16*       h1h_new  = p.h1h + pOld*32768;

    // ===== S_A: zr0(a) [wg 0-15] | zr1(s) [wg 16-31] =====
    if (wg < 16) {
      if (va) {
        SegF fs[3] = { {p.xb + (size_t)a*512, 262144},
                       {h0h_old, 1024}, {h0h_old + 512, 1024} };
        f32x4 acc0 = {0.f,0.f,0.f,0.f}, acc1 = {0.f,0.f,0.f,0.f};
        const int ntg = wg*8 + wid;
        run_phase<3,0,false>(fs, nullptr, p.wzr0, ntg, As, acc0, acc1,
                             nullptr, nullptr, zv, hv);
        epi_zr(acc0, acc1, ntg, l, p.bxz0, p.bxr0, p.z0, p.r0h);
      }
    } else {
      if (vs) {
        SegF fs[4] = { {h0h_old, 1024}, {h0h_old + 512, 1024},
                       {h1h_old2, 1024}, {h1h_old2 + 512, 1024} };
        f32x4 acc0 = {0.f,0.f,0.f,0.f}, acc1 = {0.f,0.f,0.f,0.f};
        const int ntg = (wg-16)*8 + wid;
        run_phase<4,0,false>(fs, nullptr, p.wzr1, ntg, As, acc0, acc1,
                             nullptr, nullptr, zv, hv);
        epi_zr(acc0, acc1, ntg, l, p.bxz1, p.bxr1, p.z1, p.r1h);
      }
    }
    gridbar(p.flags, ++gen);

    // ===== S_B: g0+h0(a) [wg 0-7] | g1+h1(s) [wg 8-15] | y(c) [wg 16-19] =====
    if (wg < 8) {
      if (va) {
        SegF fs[1] = { {p.xb + (size_t)a*512, 262144} };
        SegP ps[2] = { {p.r0h, h0h_old}, {p.r0h + 512, h0h_old + 512} };
        f32x4 acc0 = {0.f,0.f,0.f,0.f}, acc1 = {0.f,0.f,0.f,0.f};
        const int ntg = wg*8 + wid;
        run_phase<1,2,true>(fs, ps, p.wg0, ntg, As, acc0, acc1,
                            p.z0, h0f_old, zv, hv);
        epi_g(acc0, acc1, ntg, l, p.bxg0, zv, hv, h0f_new, h0h_new);
      }
    } else if (wg < 16) {
      if (vs) {
        SegF fs[2] = { {h0h_old, 1024}, {h0h_old + 512, 1024} };
        SegP ps[2] = { {p.r1h, h1h_old2}, {p.r1h + 512, h1h_old2 + 512} };
        f32x4 acc0 = {0.f,0.f,0.f,0.f}, acc1 = {0.f,0.f,0.f,0.f};
        const int ntg = (wg-8)*8 + wid;
        run_phase<2,2,true>(fs, ps, p.wg1, ntg, As, acc0, acc1,
                            p.z1, h1f_old2, zv, hv);
        epi_g(acc0, acc1, ntg, l, p.bxg1, zv, hv, h1f_new, h1h_new);
      }
    } else if (wg < 20) {
      if (vc) {
        SegF fs[2] = { {h1h_old2, 1024}, {h1h_old2 + 512, 1024} };
        f32x4 acc0 = {0.f,0.f,0.f,0.f}, acc1 = {0.f,0.f,0.f,0.f};
        const int ntg = (wg-16)*8 + wid;
        run_phase<2,0,false>(fs, nullptr, p.wy, ntg, As, acc0, acc1,
                             nullptr, nullptr, zv, hv);
        const int col = ntg*16 + (l&15);
        const float bias = p.bhy[col];
        const int brow = (l>>4)<<2;
        #pragma unroll
        for (int q=0;q<4;++q) {
          p.out[(size_t)(brow+q)*262144    + (size_t)c*512 + col] = acc0[q] + bias;
          p.out[(size_t)(brow+q+16)*262144 + (size_t)c*512 + col] = acc1[q] + bias;
        }
      }
    }
    gridbar(p.flags, ++gen);
  }

  // final hidden_state (B, 2, H): h0(511), h1(511) live in parity-1
  {
    const int o = wg*NTHR + tid;
    #pragma unroll
    for (int q=0;q<4;++q) {
      const int e = o + q*16384;
      const int b = e >> 11, r2 = e & 2047, lay = r2 >> 10, hcol = r2 & 1023;
      const float* hb = (lay ? p.h1f : p.h0f) + 32768 + b*1024 + hcol;
      float v;
      bload1(v, hb);
      asm volatile("s_waitcnt vmcnt(0)" ::: "memory");
      p.out[OUT_HID_OFF + (size_t)b*2048 + (size_t)lay*1024 + hcol] = v;
    }
  }
}

// ---------- host ----------
extern "C" void kernel_launch(void* const* d_in, const int* in_sizes, int n_in,
                              void* d_out, int out_size, void* d_ws, size_t ws_size,
                              hipStream_t stream) {
  GP P;
  P.x    = (const float*)d_in[0];
  P.Wxz0 = (const float*)d_in[1];  P.bxz0 = (const float*)d_in[2];  P.Whz0 = (const float*)d_in[3];
  P.Wxr0 = (const float*)d_in[4];  P.bxr0 = (const float*)d_in[5];  P.Whr0 = (const float*)d_in[6];
  P.Wxg0 = (const float*)d_in[7];  P.bxg0 = (const float*)d_in[8];  P.Whg0 = (const float*)d_in[9];
  P.Wxz1 = (const float*)d_in[10]; P.bxz1 = (const float*)d_in[11]; P.Whz1 = (const float*)d_in[12];
  P.Wxr1 = (const float*)d_in[13]; P.bxr1 = (const float*)d_in[14]; P.Whr1 = (const float*)d_in[15];
  P.Wxg1 = (const float*)d_in[16]; P.bxg1 = (const float*)d_in[17]; P.Whg1 = (const float*)d_in[18];
  P.Why  = (const float*)d_in[19]; P.bhy  = (const float*)d_in[20];
  P.out  = (float*)d_out;

  char* ws = (char*)d_ws;
  P.xb   = (_Float16*)(ws + 0);           // 16777216
  P.wzr0 = (_Float16*)(ws + 16777216);    // 6291456
  P.wzr1 = (_Float16*)(ws + 23068672);    // 8388608
  P.wg0  = (_Float16*)(ws + 31457280);    // 3145728
  P.wg1  = (_Float16*)(ws + 34603008);    // 4194304
  P.wy   = (_Float16*)(ws + 38797312);    // 1048576
  P.h0f  = (float*)   (ws + 39845888);    // 262144
  P.h1f  = (float*)   (ws + 40108032);    // 262144
  P.h0h  = (_Float16*)(ws + 40370176);    // 131072
  P.h1h  = (_Float16*)(ws + 40501248);    // 131072
  P.z0   = (float*)   (ws + 40632320);    // 131072
  P.z1   = (float*)   (ws + 40763392);    // 131072
  P.r0h  = (_Float16*)(ws + 40894464);    // 65536
  P.r1h  = (_Float16*)(ws + 40960000);    // 65536
  P.flags= (unsigned*)(ws + 41025536);    // 4096

  // zero h (both parities, f32+f16), z/r, flags
  hipMemsetAsync(ws + 39845888, 0, 41029632 - 39845888, stream);

  pack<<<dim3(9728), dim3(256), 0, stream>>>(P);

  void* args[] = { &P };
  hipLaunchCooperativeKernel((const void*)gru_main,
                             dim3(NWG), dim3(NTHR), args, 0, stream);
}

// Round 9
// 9770.850 us; speedup vs baseline: 14.7738x; 2.5445x over previous
//
#include <hip/hip_runtime.h>

#define SS 512
#define NWG 52
#define NTHR 512
#define NITER 517
#define OUT_HID_OFF 8388608   // 32*512*512

typedef _Float16 fh8 __attribute__((ext_vector_type(8)));
typedef float f32x4 __attribute__((ext_vector_type(4)));

struct GP {
  const float *x;
  const float *Wxz0,*bxz0,*Whz0,*Wxr0,*bxr0,*Whr0,*Wxg0,*bxg0,*Whg0;
  const float *Wxz1,*bxz1,*Whz1,*Wxr1,*bxr1,*Whr1,*Wxg1,*bxg1,*Whg1;
  const float *Why,*bhy;
  float *out;
  _Float16 *xb;                       // [32][512][512] f16
  _Float16 *wzr0,*wzr1,*wg0,*wg1,*wy; // packed B-fragment order
  float *h0f,*h1f;                    // [4][32][1024] f32 rings
  _Float16 *h0h,*h1h;                 // [4][32][1024] f16 rings
  float *z0,*z1;                      // [2][32][1024] f32 rings
  _Float16 *r0,*r1;                   // [2][32][1024] f16 rings (raw r)
  unsigned *fg0,*fg1;                 // 8 producer flags each (stride 32 u32)
  unsigned *flags;                    // NWG barrier flags (stride 32 u32)
};

// ---------- accessors (r5-proven) ----------
__device__ __forceinline__ float aloadf(const float* p) {
  return __hip_atomic_load(p, __ATOMIC_RELAXED, __HIP_MEMORY_SCOPE_AGENT);
}
__device__ __forceinline__ void astore(float* p, float v) {
  __hip_atomic_store(p, v, __ATOMIC_RELAXED, __HIP_MEMORY_SCOPE_AGENT);
}
__device__ __forceinline__ void bload(uint4& d, const void* p) {
  asm volatile("global_load_dwordx4 %0, %1, off sc0 sc1"
               : "=&v"(d) : "v"(p) : "memory");
}
__device__ __forceinline__ void bload1(float& d, const float* p) {
  asm volatile("global_load_dword %0, %1, off sc0 sc1"
               : "=&v"(d) : "v"(p) : "memory");
}
__device__ __forceinline__ void sstore(_Float16* pd, float v) {
  _Float16 h = (_Float16)v;
  unsigned short u; __builtin_memcpy(&u, &h, 2);
  asm volatile("global_store_short %0, %1, off sc0 sc1"
               :: "v"(pd), "v"((unsigned)u) : "memory");
}
__device__ __forceinline__ fh8 u2h(uint4 v){ fh8 r; __builtin_memcpy(&r, &v, 16); return r; }
__device__ __forceinline__ uint4 h2u(fh8 v){ uint4 r; __builtin_memcpy(&r, &v, 16); return r; }
__device__ __forceinline__ float sigmf(float v){ return 1.f/(1.f+__expf(-v)); }

// ---------- one-time pack (r5 verbatim) ----------
__global__ __launch_bounds__(256) void pack(GP p) {
  const long gid = (long)blockIdx.x*256 + threadIdx.x;
  if (gid < 1441792) {
    long u; int KC; _Float16* dst;
    if (gid < 393216)       { u=gid;         KC=48; dst=p.wzr0; }
    else if (gid < 917504)  { u=gid-393216;  KC=64; dst=p.wzr1; }
    else if (gid < 1114112) { u=gid-917504;  KC=48; dst=p.wg0;  }
    else if (gid < 1376256) { u=gid-1114112; KC=64; dst=p.wg1;  }
    else                    { u=gid-1376256; KC=32; dst=p.wy;   }
    const int per = KC*64;
    const int ntg = (int)(u/per); const int r = (int)(u%per);
    const int kc = r>>6, lane = r&63;
    const int n = ntg*16 + (lane&15);
    const int k = kc*32 + ((lane>>4)<<3);
    const float* src;
    if (gid < 393216) {
      int g = n>>10, nn = n&1023;
      src = (k<512) ? ((g?p.Wxr0:p.Wxz0) + (size_t)nn*512 + k)
                    : ((g?p.Whr0:p.Whz0) + (size_t)nn*1024 + (k-512));
    } else if (gid < 917504) {
      int g = n>>10, nn = n&1023;
      src = (k<1024) ? ((g?p.Wxr1:p.Wxz1) + (size_t)nn*1024 + k)
                     : ((g?p.Whr1:p.Whz1) + (size_t)nn*1024 + (k-1024));
    } else if (gid < 1114112) {
      src = (k<512) ? (p.Wxg0 + (size_t)n*512 + k)
                    : (p.Whg0 + (size_t)n*1024 + (k-512));
    } else if (gid < 1376256) {
      src = (k<1024) ? (p.Wxg1 + (size_t)n*1024 + k)
                     : (p.Whg1 + (size_t)n*1024 + (k-1024));
    } else {
      src = p.Why + (size_t)n*1024 + k;
    }
    float4 f0 = *(const float4*)src, f1 = *(const float4*)(src+4);
    fh8 h;
    h[0]=(_Float16)f0.x; h[1]=(_Float16)f0.y; h[2]=(_Float16)f0.z; h[3]=(_Float16)f0.w;
    h[4]=(_Float16)f1.x; h[5]=(_Float16)f1.y; h[6]=(_Float16)f1.z; h[7]=(_Float16)f1.w;
    *(fh8*)(dst + u*8) = h;
  } else if (gid < 2490368) {
    const long e = (gid - 1441792)*8;
    float4 f0 = *(const float4*)(p.x + e), f1 = *(const float4*)(p.x + e + 4);
    fh8 h;
    h[0]=(_Float16)f0.x; h[1]=(_Float16)f0.y; h[2]=(_Float16)f0.z; h[3]=(_Float16)f0.w;
    h[4]=(_Float16)f1.x; h[5]=(_Float16)f1.y; h[6]=(_Float16)f1.z; h[7]=(_Float16)f1.w;
    *(fh8*)(p.xb + e) = h;
  }
}

// ---------- grid barrier (r5 pattern, 52 WGs) ----------
__device__ __forceinline__ void gridbar(unsigned* flags, unsigned g) {
  asm volatile("s_waitcnt vmcnt(0) lgkmcnt(0)" ::: "memory");
  __syncthreads();
  if (threadIdx.x == 0)
    __hip_atomic_store(flags + (size_t)blockIdx.x*32, g,
                       __ATOMIC_RELAXED, __HIP_MEMORY_SCOPE_AGENT);
  if (threadIdx.x < NWG) {
    const unsigned* f = flags + (size_t)threadIdx.x*32;
    while (__hip_atomic_load(f, __ATOMIC_RELAXED, __HIP_MEMORY_SCOPE_AGENT) < g)
      __builtin_amdgcn_s_sleep(1);
  }
  asm volatile("" ::: "memory");
  __syncthreads();
}

// ---------- producer-flag wait: 8 flags, gen g ----------
__device__ __forceinline__ void wait8(const unsigned* fb, unsigned g) {
  if (threadIdx.x < 8) {
    const unsigned* f = fb + (size_t)threadIdx.x*32;
    while (__hip_atomic_load(f, __ATOMIC_RELAXED, __HIP_MEMORY_SCOPE_AGENT) < g)
      __builtin_amdgcn_s_sleep(1);
  }
  asm volatile("" ::: "memory");
  __syncthreads();
}

// ---------- staging helpers (r5 layout: row*4096, XOR key (row&15)<<4) ----------
__device__ __forceinline__ void issue_copy(uint4* R, const _Float16* base, int row, int s16) {
  const char* sp = (const char*)(base + (size_t)row*1024) + s16*64;
  bload(R[0], sp); bload(R[1], sp+16); bload(R[2], sp+32); bload(R[3], sp+48);
}
__device__ __forceinline__ void issue_prod(uint4* Ra, uint4* Rh,
    const _Float16* ra, const _Float16* ha, int row, int s16) {
  const char* rp = (const char*)(ra + (size_t)row*1024) + s16*64;
  const char* hp = (const char*)(ha + (size_t)row*1024) + s16*64;
  #pragma unroll
  for (int q = 0; q < 4; ++q) { bload(Ra[q], rp + q*16); bload(Rh[q], hp + q*16); }
}
__device__ __forceinline__ void issue_x(uint4* R, const _Float16* xab, int row, int s16) {
  const uint4* sp = (const uint4*)(xab + (size_t)row*262144 + (size_t)s16*32);
  R[0]=sp[0]; R[1]=sp[1]; R[2]=sp[2]; R[3]=sp[3];
}
__device__ __forceinline__ void commit4(const uint4* R, char* As, int s, int row, int s16) {
  const int key = (row & 15) << 4;
  char* d = As + (size_t)row*4096;
  const int kb0 = s*1024 + s16*64;
  #pragma unroll
  for (int q = 0; q < 4; ++q) *(uint4*)(d + ((kb0 + q*16) ^ key)) = R[q];
}
__device__ __forceinline__ void commit_prod(const uint4* Ra, const uint4* Rh,
    char* As, int s, int row, int s16) {
  const int key = (row & 15) << 4;
  char* d = As + (size_t)row*4096;
  const int kb0 = s*1024 + s16*64;
  #pragma unroll
  for (int q = 0; q < 4; ++q) {
    fh8 o = u2h(Ra[q]) * u2h(Rh[q]);
    *(uint4*)(d + ((kb0 + q*16) ^ key)) = h2u(o);
  }
}

// ---------- MFMA sweep over chunk range [k0,k1) ----------
__device__ __forceinline__ void sweep_range(const char* As, const _Float16* wpk,
    int ntg, int KC, int k0, int k1, int l, f32x4& acc0, f32x4& acc1) {
  const int lrow = l & 15, key = lrow << 4, lg16 = (l >> 4) << 4;
  const char* ab = As + (size_t)lrow*4096;
  const _Float16* wb = wpk + (size_t)ntg*KC*512 + (size_t)l*8;
  #pragma unroll 8
  for (int kk = k0; kk < k1; ++kk) {
    const int off = (kk*64 + lg16) ^ key;
    fh8 a0 = *(const fh8*)(ab + off);
    fh8 a1 = *(const fh8*)(ab + 16*4096 + off);
    fh8 b  = *(const fh8*)(wb + (size_t)kk*512);
    acc0 = __builtin_amdgcn_mfma_f32_16x16x32_f16(a0, b, acc0, 0, 0, 0);
    acc1 = __builtin_amdgcn_mfma_f32_16x16x32_f16(a1, b, acc1, 0, 0, 0);
  }
}

// ---------- epilogues (r5-proven mapping: col=lane&15, b=(lane>>4)*4+q) ----------
__device__ __forceinline__ void epi_zr(const f32x4& a0, const f32x4& a1, int ntg, int l,
    const float* bz, const float* br, float* zbuf, _Float16* rbuf) {
  const int col = (ntg << 4) | (l & 15);
  const int gate = col >> 10, cc = col & 1023;
  const float bias = gate ? br[cc] : bz[cc];
  const int brow = (l >> 4) << 2;
  #pragma unroll
  for (int q = 0; q < 4; ++q) {
    const float v0 = sigmf(a0[q]+bias), v1 = sigmf(a1[q]+bias);
    if (gate) {
      sstore(rbuf + (size_t)(brow+q)*1024 + cc, v0);
      sstore(rbuf + (size_t)(brow+q+16)*1024 + cc, v1);
    } else {
      astore(zbuf + (size_t)(brow+q)*1024 + cc, v0);
      astore(zbuf + (size_t)(brow+q+16)*1024 + cc, v1);
    }
  }
}
__device__ __forceinline__ void epi_h(const f32x4& a0, const f32x4& a1, int colB, int brow,
    const float* bgp, const float* zv, const float* hv, float* hF, _Float16* hH) {
  const float bias = bgp[colB];
  #pragma unroll
  for (int q = 0; q < 4; ++q) {
    { const float g = tanhf(a0[q]+bias);
      const float hn = zv[q]*hv[q] + (1.f-zv[q])*g;
      astore(hF + (size_t)(brow+q)*1024 + colB, hn);
      sstore(hH + (size_t)(brow+q)*1024 + colB, hn); }
    { const float g = tanhf(a1[q]+bias);
      const float hn = zv[4+q]*hv[4+q] + (1.f-zv[4+q])*g;
      astore(hF + (size_t)(brow+q+16)*1024 + colB, hn);
      sstore(hH + (size_t)(brow+q+16)*1024 + colB, hn); }
  }
}

// ---------- main persistent kernel: 1 barrier/step, producer flags ----------
__global__ __launch_bounds__(NTHR, 2) void gru_main(GP p) {
  __shared__ char As[131072];
  const int tid = threadIdx.x, wg = blockIdx.x;
  const int wid = tid >> 6, l = tid & 63;
  const int row = tid >> 4, s16 = tid & 15;
  const int brow = (l >> 4) << 2;
  unsigned gen = 0;

  for (int i = 0; i < NITER; ++i) {
    if (wg < 16) {
      // ===== ZR0: z0,r0 at step t = i =====
      if (i <= 511) {
        const int t = i;
        const int ntg = wg*8 + wid;
        f32x4 a0 = {0.f,0.f,0.f,0.f}, a1 = {0.f,0.f,0.f,0.f};
        { uint4 Rx[4];
          issue_x(Rx, p.xb + (size_t)t*512, row, s16);
          commit4(Rx, As, 0, row, s16); }          // plain loads: compiler-tracked
        __syncthreads();
        sweep_range(As, p.wzr0, ntg, 48, 0, 16, l, a0, a1);
        if (t >= 1) wait8(p.fg0, (unsigned)i);     // h0(t-1) produced THIS interval
        { const _Float16* hb = p.h0h + (size_t)((t-1)&3)*32768;
          uint4 R0[4], R1[4];
          issue_copy(R0, hb, row, s16);
          issue_copy(R1, hb+512, row, s16);
          asm volatile("s_waitcnt vmcnt(0)" ::: "memory");
          __builtin_amdgcn_sched_barrier(0);
          commit4(R0, As, 1, row, s16);
          commit4(R1, As, 2, row, s16); }
        __syncthreads();
        sweep_range(As, p.wzr0, ntg, 48, 16, 48, l, a0, a1);
        epi_zr(a0, a1, ntg, l, p.bxz0, p.bxr0,
               p.z0 + (size_t)(t&1)*32768, p.r0 + (size_t)(t&1)*32768);
      }
    } else if (wg < 32) {
      // ===== ZR1: z1,r1 at step t1 = i-2 =====
      if (i >= 2 && i <= 513) {
        const int t1 = i-2;
        const int ntg = (wg-16)*8 + wid;
        f32x4 a0 = {0.f,0.f,0.f,0.f}, a1 = {0.f,0.f,0.f,0.f};
        { const _Float16* hb = p.h0h + (size_t)(t1&3)*32768;   // h0(t1): stored @ i-1
          uint4 R0[4], R1[4];
          issue_copy(R0, hb, row, s16);
          issue_copy(R1, hb+512, row, s16);
          asm volatile("s_waitcnt vmcnt(0)" ::: "memory");
          __builtin_amdgcn_sched_barrier(0);
          commit4(R0, As, 0, row, s16);
          commit4(R1, As, 1, row, s16); }
        __syncthreads();
        sweep_range(As, p.wzr1, ntg, 64, 0, 32, l, a0, a1);
        if (t1 >= 1) wait8(p.fg1, (unsigned)i);    // h1(t1-1) produced THIS interval
        { const _Float16* hb = p.h1h + (size_t)((t1-1)&3)*32768;
          uint4 R0[4], R1[4];
          issue_copy(R0, hb, row, s16);
          issue_copy(R1, hb+512, row, s16);
          asm volatile("s_waitcnt vmcnt(0)" ::: "memory");
          __builtin_amdgcn_sched_barrier(0);
          commit4(R0, As, 2, row, s16);
          commit4(R1, As, 3, row, s16); }
        __syncthreads();
        sweep_range(As, p.wzr1, ntg, 64, 32, 64, l, a0, a1);
        epi_zr(a0, a1, ntg, l, p.bxz1, p.bxr1,
               p.z1 + (size_t)(t1&1)*32768, p.r1 + (size_t)(t1&1)*32768);
      }
    } else if (wg < 40) {
      // ===== G0: g0 + h0-update at step u = i-1 (all inputs interval-old) =====
      if (i >= 1 && i <= 512) {
        const int u = i-1;
        const int ntg = (wg-32)*8 + wid;
        const int colB = (ntg << 4) | (l & 15);
        const float*    zr    = p.z0  + (size_t)(u&1)*32768;
        const float*    hfold = p.h0f + (size_t)((u-1)&3)*32768;
        const _Float16* rr    = p.r0  + (size_t)(u&1)*32768;
        const _Float16* hh    = p.h0h + (size_t)((u-1)&3)*32768;
        float zv[8], hv[8];
        uint4 Rx[4], Ra[8], Rh[8];
        issue_x(Rx, p.xb + (size_t)u*512, row, s16);
        issue_prod(&Ra[0], &Rh[0], rr, hh, row, s16);
        issue_prod(&Ra[4], &Rh[4], rr+512, hh+512, row, s16);
        #pragma unroll
        for (int q = 0; q < 4; ++q) {
          bload1(zv[q],   zr    + (size_t)(brow+q)*1024 + colB);
          bload1(zv[4+q], zr    + (size_t)(brow+q+16)*1024 + colB);
          bload1(hv[q],   hfold + (size_t)(brow+q)*1024 + colB);
          bload1(hv[4+q], hfold + (size_t)(brow+q+16)*1024 + colB);
        }
        asm volatile("s_waitcnt vmcnt(0)" ::: "memory");
        __builtin_amdgcn_sched_barrier(0);
        commit4(Rx, As, 0, row, s16);
        commit_prod(&Ra[0], &Rh[0], As, 1, row, s16);
        commit_prod(&Ra[4], &Rh[4], As, 2, row, s16);
        __syncthreads();
        f32x4 a0 = {0.f,0.f,0.f,0.f}, a1 = {0.f,0.f,0.f,0.f};
        sweep_range(As, p.wg0, ntg, 48, 0, 48, l, a0, a1);
        epi_h(a0, a1, colB, brow, p.bxg0, zv, hv,
              p.h0f + (size_t)(u&3)*32768, p.h0h + (size_t)(u&3)*32768);
        asm volatile("s_waitcnt vmcnt(0) lgkmcnt(0)" ::: "memory");
        __syncthreads();
        if (tid == 0)
          __hip_atomic_store(p.fg0 + (size_t)(wg-32)*32, (unsigned)i,
                             __ATOMIC_RELAXED, __HIP_MEMORY_SCOPE_AGENT);
      }
    } else if (wg < 48) {
      // ===== G1: g1 + h1-update at step v = i-3 (all inputs interval-old) =====
      if (i >= 3 && i <= 514) {
        const int v = i-3;
        const int ntg = (wg-40)*8 + wid;
        const int colB = (ntg << 4) | (l & 15);
        const float*    zr    = p.z1  + (size_t)(v&1)*32768;
        const float*    hfold = p.h1f + (size_t)((v-1)&3)*32768;
        const _Float16* rr    = p.r1  + (size_t)(v&1)*32768;
        const _Float16* hh1   = p.h1h + (size_t)((v-1)&3)*32768;
        const _Float16* h0in  = p.h0h + (size_t)(v&3)*32768;   // h0(v): stored @ v+1 <= i-1
        float zv[8], hv[8];
        uint4 Rf[8], Ra[8], Rh[8];
        issue_copy(&Rf[0], h0in, row, s16);
        issue_copy(&Rf[4], h0in+512, row, s16);
        issue_prod(&Ra[0], &Rh[0], rr, hh1, row, s16);
        issue_prod(&Ra[4], &Rh[4], rr+512, hh1+512, row, s16);
        #pragma unroll
        for (int q = 0; q < 4; ++q) {
          bload1(zv[q],   zr    + (size_t)(brow+q)*1024 + colB);
          bload1(zv[4+q], zr    + (size_t)(brow+q+16)*1024 + colB);
          bload1(hv[q],   hfold + (size_t)(brow+q)*1024 + colB);
          bload1(hv[4+q], hfold + (size_t)(brow+q+16)*1024 + colB);
        }
        asm volatile("s_waitcnt vmcnt(0)" ::: "memory");
        __builtin_amdgcn_sched_barrier(0);
        commit4(&Rf[0], As, 0, row, s16);
        commit4(&Rf[4], As, 1, row, s16);
        commit_prod(&Ra[0], &Rh[0], As, 2, row, s16);
        commit_prod(&Ra[4], &Rh[4], As, 3, row, s16);
        __syncthreads();
        f32x4 a0 = {0.f,0.f,0.f,0.f}, a1 = {0.f,0.f,0.f,0.f};
        sweep_range(As, p.wg1, ntg, 64, 0, 64, l, a0, a1);
        epi_h(a0, a1, colB, brow, p.bxg1, zv, hv,
              p.h1f + (size_t)(v&3)*32768, p.h1h + (size_t)(v&3)*32768);
        asm volatile("s_waitcnt vmcnt(0) lgkmcnt(0)" ::: "memory");
        __syncthreads();
        if (tid == 0)
          __hip_atomic_store(p.fg1 + (size_t)(wg-40)*32, (unsigned)i,
                             __ATOMIC_RELAXED, __HIP_MEMORY_SCOPE_AGENT);
      }
    } else {
      // ===== Y: y at step w = i-5 (h1(w) stored @ w+3 = i-2) =====
      if (i >= 5) {
        const int w = i-5;
        const int ntg = (wg-48)*8 + wid;
        const _Float16* hb = p.h1h + (size_t)(w&3)*32768;
        uint4 R0[4], R1[4];
        issue_copy(R0, hb, row, s16);
        issue_copy(R1, hb+512, row, s16);
        asm volatile("s_waitcnt vmcnt(0)" ::: "memory");
        __builtin_amdgcn_sched_barrier(0);
        commit4(R0, As, 0, row, s16);
        commit4(R1, As, 1, row, s16);
        __syncthreads();
        f32x4 a0 = {0.f,0.f,0.f,0.f}, a1 = {0.f,0.f,0.f,0.f};
        sweep_range(As, p.wy, ntg, 32, 0, 32, l, a0, a1);
        const int col = (ntg << 4) | (l & 15);
        const float bias = p.bhy[col];
        #pragma unroll
        for (int q = 0; q < 4; ++q) {
          p.out[(size_t)(brow+q)*262144    + (size_t)w*512 + col] = a0[q] + bias;
          p.out[(size_t)(brow+q+16)*262144 + (size_t)w*512 + col] = a1[q] + bias;
        }
      }
    }
    gridbar(p.flags, ++gen);
  }

  // final hidden_state (B, 2, H): h0(511) and h1(511) live in ring slot 511&3 = 3
  for (int e = wg*NTHR + tid; e < 65536; e += NWG*NTHR) {
    const int b = e >> 11, r2 = e & 2047, lay = r2 >> 10, hcol = r2 & 1023;
    const float* hb = (lay ? p.h1f : p.h0f) + (size_t)3*32768 + b*1024 + hcol;
    p.out[OUT_HID_OFF + (size_t)b*2048 + (size_t)lay*1024 + hcol] = aloadf(hb);
  }
}

// ---------- host ----------
extern "C" void kernel_launch(void* const* d_in, const int* in_sizes, int n_in,
                              void* d_out, int out_size, void* d_ws, size_t ws_size,
                              hipStream_t stream) {
  GP P;
  P.x    = (const float*)d_in[0];
  P.Wxz0 = (const float*)d_in[1];  P.bxz0 = (const float*)d_in[2];  P.Whz0 = (const float*)d_in[3];
  P.Wxr0 = (const float*)d_in[4];  P.bxr0 = (const float*)d_in[5];  P.Whr0 = (const float*)d_in[6];
  P.Wxg0 = (const float*)d_in[7];  P.bxg0 = (const float*)d_in[8];  P.Whg0 = (const float*)d_in[9];
  P.Wxz1 = (const float*)d_in[10]; P.bxz1 = (const float*)d_in[11]; P.Whz1 = (const float*)d_in[12];
  P.Wxr1 = (const float*)d_in[13]; P.bxr1 = (const float*)d_in[14]; P.Whr1 = (const float*)d_in[15];
  P.Wxg1 = (const float*)d_in[16]; P.bxg1 = (const float*)d_in[17]; P.Whg1 = (const float*)d_in[18];
  P.Why  = (const float*)d_in[19]; P.bhy  = (const float*)d_in[20];
  P.out  = (float*)d_out;

  char* ws = (char*)d_ws;
  P.xb   = (_Float16*)(ws + 0);           // 16777216
  P.wzr0 = (_Float16*)(ws + 16777216);    // 6291456
  P.wzr1 = (_Float16*)(ws + 23068672);    // 8388608
  P.wg0  = (_Float16*)(ws + 31457280);    // 3145728
  P.wg1  = (_Float16*)(ws + 34603008);    // 4194304
  P.wy   = (_Float16*)(ws + 38797312);    // 1048576
  P.h0f  = (float*)   (ws + 39845888);    // 524288  (4-ring f32)
  P.h1f  = (float*)   (ws + 40370176);    // 524288
  P.h0h  = (_Float16*)(ws + 40894464);    // 262144  (4-ring f16)
  P.h1h  = (_Float16*)(ws + 41156608);    // 262144
  P.z0   = (float*)   (ws + 41418752);    // 262144  (2-ring f32)
  P.z1   = (float*)   (ws + 41680896);    // 262144
  P.r0   = (_Float16*)(ws + 41943040);    // 131072  (2-ring f16)
  P.r1   = (_Float16*)(ws + 42074112);    // 131072
  P.fg0  = (unsigned*)(ws + 42205184);    // 1024
  P.fg1  = (unsigned*)(ws + 42206208);    // 1024
  P.flags= (unsigned*)(ws + 42207232);    // 6656

  // zero all rings + flags (42213888 - 39845888 bytes)
  hipMemsetAsync(ws + 39845888, 0, 42213888 - 39845888, stream);

  pack<<<dim3(9728), dim3(256), 0, stream>>>(P);

  void* args[] = { &P };
  hipError_t err = hipLaunchCooperativeKernel((const void*)gru_main,
                                              dim3(NWG), dim3(NTHR), args, 0, stream);
  if (err != hipSuccess) {
    (void)hipGetLastError();   // clear sticky error, fall back to plain launch
    gru_main<<<dim3(NWG), dim3(NTHR), 0, stream>>>(P);
  }
}

// Round 10
// 7824.579 us; speedup vs baseline: 18.4486x; 1.2487x over previous
//
#include <hip/hip_runtime.h>

#define SS 512
#define NWG 52
#define NTHR 512
#define OUT_HID_OFF 8388608   // 32*512*512

typedef _Float16 fh8 __attribute__((ext_vector_type(8)));
typedef float f32x4 __attribute__((ext_vector_type(4)));

struct GP {
  const float *x;
  const float *Wxz0,*bxz0,*Whz0,*Wxr0,*bxr0,*Whr0,*Wxg0,*bxg0,*Whg0;
  const float *Wxz1,*bxz1,*Whz1,*Wxr1,*bxr1,*Whr1,*Wxg1,*bxg1,*Whg1;
  const float *Why,*bhy;
  float *out;
  _Float16 *xb;                       // [32][512][512] f16
  _Float16 *wzr0,*wzr1,*wg0,*wg1,*wy; // packed B-fragment order
  float *h0f,*h1f;                    // [4][32][1024] f32 rings
  _Float16 *h0h,*h1h;                 // [4][32][1024] f16 rings
  float *z0,*z1;                      // [2][32][1024] f32 rings
  _Float16 *r0,*r1;                   // [2][32][1024] f16 rings
  unsigned *fg0,*fg1;                 // 8 flags each (stride 32 u32)
  unsigned *fzr0,*fzr1;               // 16 flags each
  unsigned *fy;                       // 4 flags
};

// ---------- accessors (r9-proven) ----------
__device__ __forceinline__ void astore(float* p, float v) {
  __hip_atomic_store(p, v, __ATOMIC_RELAXED, __HIP_MEMORY_SCOPE_AGENT);
}
__device__ __forceinline__ void bload(uint4& d, const void* p) {
  asm volatile("global_load_dwordx4 %0, %1, off sc0 sc1"
               : "=&v"(d) : "v"(p) : "memory");
}
__device__ __forceinline__ void bload1(float& d, const float* p) {
  asm volatile("global_load_dword %0, %1, off sc0 sc1"
               : "=&v"(d) : "v"(p) : "memory");
}
__device__ __forceinline__ void sstore(_Float16* pd, float v) {
  _Float16 h = (_Float16)v;
  unsigned short u; __builtin_memcpy(&u, &h, 2);
  asm volatile("global_store_short %0, %1, off sc0 sc1"
               :: "v"(pd), "v"((unsigned)u) : "memory");
}
__device__ __forceinline__ fh8 u2h(uint4 v){ fh8 r; __builtin_memcpy(&r, &v, 16); return r; }
__device__ __forceinline__ uint4 h2u(fh8 v){ uint4 r; __builtin_memcpy(&r, &v, 16); return r; }
__device__ __forceinline__ float sigmf(float v){ return 1.f/(1.f+__expf(-v)); }

// ---------- one-time pack (r9 verbatim) ----------
__global__ __launch_bounds__(256) void pack(GP p) {
  const long gid = (long)blockIdx.x*256 + threadIdx.x;
  if (gid < 1441792) {
    long u; int KC; _Float16* dst;
    if (gid < 393216)       { u=gid;         KC=48; dst=p.wzr0; }
    else if (gid < 917504)  { u=gid-393216;  KC=64; dst=p.wzr1; }
    else if (gid < 1114112) { u=gid-917504;  KC=48; dst=p.wg0;  }
    else if (gid < 1376256) { u=gid-1114112; KC=64; dst=p.wg1;  }
    else                    { u=gid-1376256; KC=32; dst=p.wy;   }
    const int per = KC*64;
    const int ntg = (int)(u/per); const int r = (int)(u%per);
    const int kc = r>>6, lane = r&63;
    const int n = ntg*16 + (lane&15);
    const int k = kc*32 + ((lane>>4)<<3);
    const float* src;
    if (gid < 393216) {
      int g = n>>10, nn = n&1023;
      src = (k<512) ? ((g?p.Wxr0:p.Wxz0) + (size_t)nn*512 + k)
                    : ((g?p.Whr0:p.Whz0) + (size_t)nn*1024 + (k-512));
    } else if (gid < 917504) {
      int g = n>>10, nn = n&1023;
      src = (k<1024) ? ((g?p.Wxr1:p.Wxz1) + (size_t)nn*1024 + k)
                     : ((g?p.Whr1:p.Whz1) + (size_t)nn*1024 + (k-1024));
    } else if (gid < 1114112) {
      src = (k<512) ? (p.Wxg0 + (size_t)n*512 + k)
                    : (p.Whg0 + (size_t)n*1024 + (k-512));
    } else if (gid < 1376256) {
      src = (k<1024) ? (p.Wxg1 + (size_t)n*1024 + k)
                     : (p.Whg1 + (size_t)n*1024 + (k-1024));
    } else {
      src = p.Why + (size_t)n*1024 + k;
    }
    float4 f0 = *(const float4*)src, f1 = *(const float4*)(src+4);
    fh8 h;
    h[0]=(_Float16)f0.x; h[1]=(_Float16)f0.y; h[2]=(_Float16)f0.z; h[3]=(_Float16)f0.w;
    h[4]=(_Float16)f1.x; h[5]=(_Float16)f1.y; h[6]=(_Float16)f1.z; h[7]=(_Float16)f1.w;
    *(fh8*)(dst + u*8) = h;
  } else if (gid < 2490368) {
    const long e = (gid - 1441792)*8;
    float4 f0 = *(const float4*)(p.x + e), f1 = *(const float4*)(p.x + e + 4);
    fh8 h;
    h[0]=(_Float16)f0.x; h[1]=(_Float16)f0.y; h[2]=(_Float16)f0.z; h[3]=(_Float16)f0.w;
    h[4]=(_Float16)f1.x; h[5]=(_Float16)f1.y; h[6]=(_Float16)f1.z; h[7]=(_Float16)f1.w;
    *(fh8*)(p.xb + e) = h;
  }
}

// ---------- dataflow sync ----------
// flag value = (completed step) + 1; flags memset to 0 ("done step -1").
__device__ __forceinline__ void waitf(const unsigned* fb, int n, int need) {
  if (need > 0) {
    if ((int)threadIdx.x < n) {
      const unsigned* f = fb + (size_t)threadIdx.x*32;
      while ((int)__hip_atomic_load(f, __ATOMIC_RELAXED, __HIP_MEMORY_SCOPE_AGENT) < need)
        __builtin_amdgcn_s_sleep(1);
    }
    asm volatile("" ::: "memory");
    __syncthreads();
  }
}
__device__ __forceinline__ void setflag(unsigned* f, unsigned v) {
  asm volatile("s_waitcnt vmcnt(0) lgkmcnt(0)" ::: "memory");
  __syncthreads();   // all waves drained -> data LLC-visible before flag
  if (threadIdx.x == 0)
    __hip_atomic_store(f, v, __ATOMIC_RELAXED, __HIP_MEMORY_SCOPE_AGENT);
}

// ---------- staging helpers (r9 verbatim; layout row*4096, XOR key) ----------
__device__ __forceinline__ void issue_copy(uint4* R, const _Float16* base, int row, int s16) {
  const char* sp = (const char*)(base + (size_t)row*1024) + s16*64;
  bload(R[0], sp); bload(R[1], sp+16); bload(R[2], sp+32); bload(R[3], sp+48);
}
__device__ __forceinline__ void issue_prod(uint4* Ra, uint4* Rh,
    const _Float16* ra, const _Float16* ha, int row, int s16) {
  const char* rp = (const char*)(ra + (size_t)row*1024) + s16*64;
  const char* hp = (const char*)(ha + (size_t)row*1024) + s16*64;
  #pragma unroll
  for (int q = 0; q < 4; ++q) { bload(Ra[q], rp + q*16); bload(Rh[q], hp + q*16); }
}
__device__ __forceinline__ void issue_x(uint4* R, const _Float16* xab, int row, int s16) {
  const uint4* sp = (const uint4*)(xab + (size_t)row*262144 + (size_t)s16*32);
  R[0]=sp[0]; R[1]=sp[1]; R[2]=sp[2]; R[3]=sp[3];
}
__device__ __forceinline__ void commit4(const uint4* R, char* As, int s, int row, int s16) {
  const int key = (row & 15) << 4;
  char* d = As + (size_t)row*4096;
  const int kb0 = s*1024 + s16*64;
  #pragma unroll
  for (int q = 0; q < 4; ++q) *(uint4*)(d + ((kb0 + q*16) ^ key)) = R[q];
}
__device__ __forceinline__ void commit_prod(const uint4* Ra, const uint4* Rh,
    char* As, int s, int row, int s16) {
  const int key = (row & 15) << 4;
  char* d = As + (size_t)row*4096;
  const int kb0 = s*1024 + s16*64;
  #pragma unroll
  for (int q = 0; q < 4; ++q) {
    fh8 o = u2h(Ra[q]) * u2h(Rh[q]);
    *(uint4*)(d + ((kb0 + q*16) ^ key)) = h2u(o);
  }
}

// ---------- MFMA sweep (r9 verbatim) ----------
__device__ __forceinline__ void sweep_range(const char* As, const _Float16* wpk,
    int ntg, int KC, int k0, int k1, int l, f32x4& acc0, f32x4& acc1) {
  const int lrow = l & 15, key = lrow << 4, lg16 = (l >> 4) << 4;
  const char* ab = As + (size_t)lrow*4096;
  const _Float16* wb = wpk + (size_t)ntg*KC*512 + (size_t)l*8;
  #pragma unroll 8
  for (int kk = k0; kk < k1; ++kk) {
    const int off = (kk*64 + lg16) ^ key;
    fh8 a0 = *(const fh8*)(ab + off);
    fh8 a1 = *(const fh8*)(ab + 16*4096 + off);
    fh8 b  = *(const fh8*)(wb + (size_t)kk*512);
    acc0 = __builtin_amdgcn_mfma_f32_16x16x32_f16(a0, b, acc0, 0, 0, 0);
    acc1 = __builtin_amdgcn_mfma_f32_16x16x32_f16(a1, b, acc1, 0, 0, 0);
  }
}

// ---------- epilogue zr (r9 verbatim) ----------
__device__ __forceinline__ void epi_zr(const f32x4& a0, const f32x4& a1, int ntg, int l,
    const float* bz, const float* br, float* zbuf, _Float16* rbuf) {
  const int col = (ntg << 4) | (l & 15);
  const int gate = col >> 10, cc = col & 1023;
  const float bias = gate ? br[cc] : bz[cc];
  const int brow = (l >> 4) << 2;
  #pragma unroll
  for (int q = 0; q < 4; ++q) {
    const float v0 = sigmf(a0[q]+bias), v1 = sigmf(a1[q]+bias);
    if (gate) {
      sstore(rbuf + (size_t)(brow+q)*1024 + cc, v0);
      sstore(rbuf + (size_t)(brow+q+16)*1024 + cc, v1);
    } else {
      astore(zbuf + (size_t)(brow+q)*1024 + cc, v0);
      astore(zbuf + (size_t)(brow+q+16)*1024 + cc, v1);
    }
  }
}

// ---------- main persistent kernel: pure dataflow, no grid barrier ----------
__global__ __launch_bounds__(NTHR, 2) void gru_main(GP p) {
  __shared__ char As[131072];
  const int tid = threadIdx.x, wg = blockIdx.x;
  const int wid = tid >> 6, l = tid & 63;
  const int row = tid >> 4, s16 = tid & 15;
  const int brow = (l >> 4) << 2;

  if (wg < 16) {
    // ================= ZR0: z0,r0(t), t = 0..511 =================
    const int ntg = wg*8 + wid;
    for (int t = 0; t < SS; ++t) {
      { uint4 Rx[4];
        issue_x(Rx, p.xb + (size_t)t*512, row, s16);
        commit4(Rx, As, 0, row, s16); }
      __syncthreads();
      f32x4 a0 = {0.f,0.f,0.f,0.f}, a1 = {0.f,0.f,0.f,0.f};
      sweep_range(As, p.wzr0, ntg, 48, 0, 16, l, a0, a1);
      waitf(p.fg0, 8, t);                        // h0(t-1) done
      { const _Float16* hb = p.h0h + (size_t)((t-1)&3)*32768;
        uint4 R0[4], R1[4];
        issue_copy(R0, hb, row, s16);
        issue_copy(R1, hb+512, row, s16);
        asm volatile("s_waitcnt vmcnt(0)" ::: "memory");
        __builtin_amdgcn_sched_barrier(0);
        commit4(R0, As, 1, row, s16);
        commit4(R1, As, 2, row, s16); }
      __syncthreads();
      sweep_range(As, p.wzr0, ntg, 48, 16, 48, l, a0, a1);
      epi_zr(a0, a1, ntg, l, p.bxz0, p.bxr0,
             p.z0 + (size_t)(t&1)*32768, p.r0 + (size_t)(t&1)*32768);
      setflag(p.fzr0 + (size_t)wg*32, (unsigned)(t+1));
    }
  } else if (wg < 32) {
    // ================= ZR1: z1,r1(t), t = 0..511 =================
    const int ntg = (wg-16)*8 + wid;
    for (int t = 0; t < SS; ++t) {
      waitf(p.fg0, 8, t+1);                      // h0(t) done
      { const _Float16* hb = p.h0h + (size_t)(t&3)*32768;
        uint4 R0[4], R1[4];
        issue_copy(R0, hb, row, s16);
        issue_copy(R1, hb+512, row, s16);
        asm volatile("s_waitcnt vmcnt(0)" ::: "memory");
        __builtin_amdgcn_sched_barrier(0);
        commit4(R0, As, 0, row, s16);
        commit4(R1, As, 1, row, s16); }
      __syncthreads();
      f32x4 a0 = {0.f,0.f,0.f,0.f}, a1 = {0.f,0.f,0.f,0.f};
      sweep_range(As, p.wzr1, ntg, 64, 0, 32, l, a0, a1);
      waitf(p.fg1, 8, t);                        // h1(t-1) done
      { const _Float16* hb = p.h1h + (size_t)((t-1)&3)*32768;
        uint4 R0[4], R1[4];
        issue_copy(R0, hb, row, s16);
        issue_copy(R1, hb+512, row, s16);
        asm volatile("s_waitcnt vmcnt(0)" ::: "memory");
        __builtin_amdgcn_sched_barrier(0);
        commit4(R0, As, 2, row, s16);
        commit4(R1, As, 3, row, s16); }
      __syncthreads();
      sweep_range(As, p.wzr1, ntg, 64, 32, 64, l, a0, a1);
      epi_zr(a0, a1, ntg, l, p.bxz1, p.bxr1,
             p.z1 + (size_t)(t&1)*32768, p.r1 + (size_t)(t&1)*32768);
      setflag(p.fzr1 + (size_t)(wg-16)*32, (unsigned)(t+1));
    }
  } else if (wg < 40) {
    // ================= G0: g0 + h0-update(u), u = 0..511 =================
    const int gi = wg - 32;
    const int ntg = gi*8 + wid;
    const int colB = (ntg << 4) | (l & 15);
    const float biasB = p.bxg0[colB];
    float hv[8];
    #pragma unroll
    for (int q = 0; q < 8; ++q) hv[q] = 0.f;     // h0(-1) = 0
    for (int u = 0; u < SS; ++u) {
      { uint4 Rx[4];
        issue_x(Rx, p.xb + (size_t)u*512, row, s16);
        commit4(Rx, As, 0, row, s16); }
      __syncthreads();
      f32x4 a0 = {0.f,0.f,0.f,0.f}, a1 = {0.f,0.f,0.f,0.f};
      sweep_range(As, p.wg0, ntg, 48, 0, 16, l, a0, a1);
      waitf(p.fzr0, 16, u+1);                    // z0,r0(u)
      waitf(p.fg0,  8,  u);                      // full h0h(u-1)
      waitf(p.fzr1, 16, u-3);                    // h0-ring back-pressure
      waitf(p.fg1,  8,  u-3);
      { const float*    zr = p.z0 + (size_t)(u&1)*32768;
        const _Float16* rr = p.r0 + (size_t)(u&1)*32768;
        const _Float16* hh = p.h0h + (size_t)((u-1)&3)*32768;
        float zv[8];
        uint4 Ra[8], Rh[8];
        issue_prod(&Ra[0], &Rh[0], rr, hh, row, s16);
        issue_prod(&Ra[4], &Rh[4], rr+512, hh+512, row, s16);
        #pragma unroll
        for (int q = 0; q < 4; ++q) {
          bload1(zv[q],   zr + (size_t)(brow+q)*1024 + colB);
          bload1(zv[4+q], zr + (size_t)(brow+q+16)*1024 + colB);
        }
        asm volatile("s_waitcnt vmcnt(0)" ::: "memory");
        __builtin_amdgcn_sched_barrier(0);
        commit_prod(&Ra[0], &Rh[0], As, 1, row, s16);
        commit_prod(&Ra[4], &Rh[4], As, 2, row, s16);
        __syncthreads();
        sweep_range(As, p.wg0, ntg, 48, 16, 48, l, a0, a1);
        float* hF = p.h0f + (size_t)(u&3)*32768;
        _Float16* hH = p.h0h + (size_t)(u&3)*32768;
        #pragma unroll
        for (int q = 0; q < 4; ++q) {
          { const float g = tanhf(a0[q]+biasB);
            const float hn = zv[q]*hv[q] + (1.f-zv[q])*g;
            hv[q] = hn;
            astore(hF + (size_t)(brow+q)*1024 + colB, hn);
            sstore(hH + (size_t)(brow+q)*1024 + colB, hn); }
          { const float g = tanhf(a1[q]+biasB);
            const float hn = zv[4+q]*hv[4+q] + (1.f-zv[4+q])*g;
            hv[4+q] = hn;
            astore(hF + (size_t)(brow+q+16)*1024 + colB, hn);
            sstore(hH + (size_t)(brow+q+16)*1024 + colB, hn); }
        }
      }
      setflag(p.fg0 + (size_t)gi*32, (unsigned)(u+1));
    }
    #pragma unroll
    for (int q = 0; q < 4; ++q) {                // hidden_state layer 0
      p.out[OUT_HID_OFF + (size_t)(brow+q)*2048 + colB]    = hv[q];
      p.out[OUT_HID_OFF + (size_t)(brow+q+16)*2048 + colB] = hv[4+q];
    }
  } else if (wg < 48) {
    // ================= G1: g1 + h1-update(v), v = 0..511 =================
    const int gi = wg - 40;
    const int ntg = gi*8 + wid;
    const int colB = (ntg << 4) | (l & 15);
    const float biasB = p.bxg1[colB];
    float hv[8];
    #pragma unroll
    for (int q = 0; q < 8; ++q) hv[q] = 0.f;     // h1(-1) = 0
    for (int v = 0; v < SS; ++v) {
      waitf(p.fg0, 8, v+1);                      // h0(v) done (usually instant)
      { const _Float16* hb = p.h0h + (size_t)(v&3)*32768;
        uint4 R0[4], R1[4];
        issue_copy(R0, hb, row, s16);
        issue_copy(R1, hb+512, row, s16);
        asm volatile("s_waitcnt vmcnt(0)" ::: "memory");
        __builtin_amdgcn_sched_barrier(0);
        commit4(R0, As, 0, row, s16);
        commit4(R1, As, 1, row, s16); }
      __syncthreads();
      f32x4 a0 = {0.f,0.f,0.f,0.f}, a1 = {0.f,0.f,0.f,0.f};
      sweep_range(As, p.wg1, ntg, 64, 0, 32, l, a0, a1);
      waitf(p.fzr1, 16, v+1);                    // z1,r1(v)
      waitf(p.fg1,  8,  v);                      // full h1h(v-1)
      waitf(p.fy,   4,  v-3);                    // h1-ring back-pressure (Y)
      { const float*    zr = p.z1 + (size_t)(v&1)*32768;
        const _Float16* rr = p.r1 + (size_t)(v&1)*32768;
        const _Float16* hh = p.h1h + (size_t)((v-1)&3)*32768;
        float zv[8];
        uint4 Ra[8], Rh[8];
        issue_prod(&Ra[0], &Rh[0], rr, hh, row, s16);
        issue_prod(&Ra[4], &Rh[4], rr+512, hh+512, row, s16);
        #pragma unroll
        for (int q = 0; q < 4; ++q) {
          bload1(zv[q],   zr + (size_t)(brow+q)*1024 + colB);
          bload1(zv[4+q], zr + (size_t)(brow+q+16)*1024 + colB);
        }
        asm volatile("s_waitcnt vmcnt(0)" ::: "memory");
        __builtin_amdgcn_sched_barrier(0);
        commit_prod(&Ra[0], &Rh[0], As, 2, row, s16);
        commit_prod(&Ra[4], &Rh[4], As, 3, row, s16);
        __syncthreads();
        sweep_range(As, p.wg1, ntg, 64, 32, 64, l, a0, a1);
        float* hF = p.h1f + (size_t)(v&3)*32768;
        _Float16* hH = p.h1h + (size_t)(v&3)*32768;
        #pragma unroll
        for (int q = 0; q < 4; ++q) {
          { const float g = tanhf(a0[q]+biasB);
            const float hn = zv[q]*hv[q] + (1.f-zv[q])*g;
            hv[q] = hn;
            astore(hF + (size_t)(brow+q)*1024 + colB, hn);
            sstore(hH + (size_t)(brow+q)*1024 + colB, hn); }
          { const float g = tanhf(a1[q]+biasB);
            const float hn = zv[4+q]*hv[4+q] + (1.f-zv[4+q])*g;
            hv[4+q] = hn;
            astore(hF + (size_t)(brow+q+16)*1024 + colB, hn);
            sstore(hH + (size_t)(brow+q+16)*1024 + colB, hn); }
        }
      }
      setflag(p.fg1 + (size_t)gi*32, (unsigned)(v+1));
    }
    #pragma unroll
    for (int q = 0; q < 4; ++q) {                // hidden_state layer 1
      p.out[OUT_HID_OFF + (size_t)(brow+q)*2048 + 1024 + colB]    = hv[q];
      p.out[OUT_HID_OFF + (size_t)(brow+q+16)*2048 + 1024 + colB] = hv[4+q];
    }
  } else {
    // ================= Y: y(w), w = 0..511 =================
    const int ntg = (wg-48)*8 + wid;
    const int col = (ntg << 4) | (l & 15);
    const float bias = p.bhy[col];
    for (int w = 0; w < SS; ++w) {
      waitf(p.fg1, 8, w+1);                      // h1(w) done
      { const _Float16* hb = p.h1h + (size_t)(w&3)*32768;
        uint4 R0[4], R1[4];
        issue_copy(R0, hb, row, s16);
        issue_copy(R1, hb+512, row, s16);
        asm volatile("s_waitcnt vmcnt(0)" ::: "memory");
        __builtin_amdgcn_sched_barrier(0);
        commit4(R0, As, 0, row, s16);
        commit4(R1, As, 1, row, s16); }
      __syncthreads();
      f32x4 a0 = {0.f,0.f,0.f,0.f}, a1 = {0.f,0.f,0.f,0.f};
      sweep_range(As, p.wy, ntg, 32, 0, 32, l, a0, a1);
      #pragma unroll
      for (int q = 0; q < 4; ++q) {
        p.out[(size_t)(brow+q)*262144    + (size_t)w*512 + col] = a0[q] + bias;
        p.out[(size_t)(brow+q+16)*262144 + (size_t)w*512 + col] = a1[q] + bias;
      }
      setflag(p.fy + (size_t)(wg-48)*32, (unsigned)(w+1));
    }
  }
}

// ---------- host ----------
extern "C" void kernel_launch(void* const* d_in, const int* in_sizes, int n_in,
                              void* d_out, int out_size, void* d_ws, size_t ws_size,
                              hipStream_t stream) {
  GP P;
  P.x    = (const float*)d_in[0];
  P.Wxz0 = (const float*)d_in[1];  P.bxz0 = (const float*)d_in[2];  P.Whz0 = (const float*)d_in[3];
  P.Wxr0 = (const float*)d_in[4];  P.bxr0 = (const float*)d_in[5];  P.Whr0 = (const float*)d_in[6];
  P.Wxg0 = (const float*)d_in[7];  P.bxg0 = (const float*)d_in[8];  P.Whg0 = (const float*)d_in[9];
  P.Wxz1 = (const float*)d_in[10]; P.bxz1 = (const float*)d_in[11]; P.Whz1 = (const float*)d_in[12];
  P.Wxr1 = (const float*)d_in[13]; P.bxr1 = (const float*)d_in[14]; P.Whr1 = (const float*)d_in[15];
  P.Wxg1 = (const float*)d_in[16]; P.bxg1 = (const float*)d_in[17]; P.Whg1 = (const float*)d_in[18];
  P.Why  = (const float*)d_in[19]; P.bhy  = (const float*)d_in[20];
  P.out  = (float*)d_out;

  char* ws = (char*)d_ws;
  P.xb   = (_Float16*)(ws + 0);           // 16777216
  P.wzr0 = (_Float16*)(ws + 16777216);    // 6291456
  P.wzr1 = (_Float16*)(ws + 23068672);    // 8388608
  P.wg0  = (_Float16*)(ws + 31457280);    // 3145728
  P.wg1  = (_Float16*)(ws + 34603008);    // 4194304
  P.wy   = (_Float16*)(ws + 38797312);    // 1048576
  P.h0f  = (float*)   (ws + 39845888);    // 524288  (4-ring f32)
  P.h1f  = (float*)   (ws + 40370176);    // 524288
  P.h0h  = (_Float16*)(ws + 40894464);    // 262144  (4-ring f16)
  P.h1h  = (_Float16*)(ws + 41156608);    // 262144
  P.z0   = (float*)   (ws + 41418752);    // 262144  (2-ring f32)
  P.z1   = (float*)   (ws + 41680896);    // 262144
  P.r0   = (_Float16*)(ws + 41943040);    // 131072  (2-ring f16)
  P.r1   = (_Float16*)(ws + 42074112);    // 131072
  P.fg0  = (unsigned*)(ws + 42205184);    // 1024
  P.fg1  = (unsigned*)(ws + 42206208);    // 1024
  P.fzr0 = (unsigned*)(ws + 42207232);    // 2048
  P.fzr1 = (unsigned*)(ws + 42209280);    // 2048
  P.fy   = (unsigned*)(ws + 42211328);    // 512

  // zero all rings + flags
  hipMemsetAsync(ws + 39845888, 0, 42213888 - 39845888, stream);

  pack<<<dim3(9728), dim3(256), 0, stream>>>(P);

  void* args[] = { &P };
  hipError_t err = hipLaunchCooperativeKernel((const void*)gru_main,
                                              dim3(NWG), dim3(NTHR), args, 0, stream);
  if (err != hipSuccess) {
    (void)hipGetLastError();   // clear sticky error, fall back to plain launch
    gru_main<<<dim3(NWG), dim3(NTHR), 0, stream>>>(P);
  }
}